// Round 1
// baseline (1161.817 us; speedup 1.0000x reference)
//
#include <hip/hip_runtime.h>
#include <hip/hip_bf16.h>
#include <cstdint>

#define S_LEN 2048
#define D_MOD 1024
#define N_HEADS 16
#define DK 64
#define D_FF 4096

typedef __bf16 bf16x8 __attribute__((ext_vector_type(8)));
typedef float f32x4 __attribute__((ext_vector_type(4)));

#define MFMA16(a, b, c) __builtin_amdgcn_mfma_f32_16x16x32_bf16((a), (b), (c), 0, 0, 0)

// ---------------------------------------------------------------------------
// Weight transpose + f32->bf16 convert:  W[K][N] f32  ->  WT[N][K] bf16
// ---------------------------------------------------------------------------
__global__ __launch_bounds__(256)
void transpose_f32_bf16(const float* __restrict__ W, __bf16* __restrict__ WT, int K, int N)
{
    __shared__ float tile[32][33];
    int tx = threadIdx.x & 31, ty = threadIdx.x >> 5;  // 32 x 8
    int n0 = blockIdx.x * 32, k0 = blockIdx.y * 32;
    for (int i = 0; i < 4; i++)
        tile[ty + i * 8][tx] = W[(size_t)(k0 + ty + i * 8) * N + n0 + tx];
    __syncthreads();
    for (int i = 0; i < 4; i++)
        WT[(size_t)(n0 + ty + i * 8) * K + k0 + tx] = (__bf16)tile[tx][ty + i * 8];
}

// ---------------------------------------------------------------------------
// Per-head V transpose: v[s][h*64+d] bf16 -> VT[h][d][s] bf16
// ---------------------------------------------------------------------------
__global__ __launch_bounds__(256)
void vhead_transpose(const __bf16* __restrict__ v, __bf16* __restrict__ vt)
{
    __shared__ __bf16 tile[32][33];
    int tx = threadIdx.x & 31, ty = threadIdx.x >> 5;
    int s0 = blockIdx.x * 32;
    int d0 = blockIdx.y * 32;
    int h = blockIdx.z;
    for (int i = 0; i < 4; i++)
        tile[ty + i * 8][tx] = v[(size_t)(s0 + ty + i * 8) * D_MOD + h * DK + d0 + tx];
    __syncthreads();
    for (int i = 0; i < 4; i++)
        vt[(size_t)(h * DK + d0 + ty + i * 8) * S_LEN + s0 + tx] = tile[tx][ty + i * 8];
}

// ---------------------------------------------------------------------------
// LayerNorm: y = g*(x-mean)/(std+eps)+b ; writes bf16 (and optional f32)
// one block per row of 1024
// ---------------------------------------------------------------------------
__global__ __launch_bounds__(256)
void ln_kernel(const float* __restrict__ x, const float* __restrict__ gamma,
               const float* __restrict__ beta, __bf16* __restrict__ outb,
               float* __restrict__ outf)
{
    int row = blockIdx.x;
    int tid = threadIdx.x;
    const float4 v = ((const float4*)(x + (size_t)row * D_MOD))[tid];
    float s = v.x + v.y + v.z + v.w;
    float sq = v.x * v.x + v.y * v.y + v.z * v.z + v.w * v.w;
    for (int off = 32; off; off >>= 1) {
        s += __shfl_down(s, off);
        sq += __shfl_down(sq, off);
    }
    __shared__ float red[8];
    int wid = tid >> 6;
    if ((tid & 63) == 0) { red[wid] = s; red[wid + 4] = sq; }
    __syncthreads();
    s = red[0] + red[1] + red[2] + red[3];
    sq = red[4] + red[5] + red[6] + red[7];
    float mean = s * (1.f / D_MOD);
    float var = sq * (1.f / D_MOD) - mean * mean;
    var = fmaxf(var, 0.f);
    float inv = 1.f / (sqrtf(var) + 1e-6f);
    float4 gv = ((const float4*)gamma)[tid];
    float4 bv = ((const float4*)beta)[tid];
    float y0 = gv.x * ((v.x - mean) * inv) + bv.x;
    float y1 = gv.y * ((v.y - mean) * inv) + bv.y;
    float y2 = gv.z * ((v.z - mean) * inv) + bv.z;
    float y3 = gv.w * ((v.w - mean) * inv) + bv.w;
    unsigned short u0 = __builtin_bit_cast(unsigned short, (__bf16)y0);
    unsigned short u1 = __builtin_bit_cast(unsigned short, (__bf16)y1);
    unsigned short u2 = __builtin_bit_cast(unsigned short, (__bf16)y2);
    unsigned short u3 = __builtin_bit_cast(unsigned short, (__bf16)y3);
    uint2 pk;
    pk.x = (unsigned)u0 | ((unsigned)u1 << 16);
    pk.y = (unsigned)u2 | ((unsigned)u3 << 16);
    ((uint2*)(outb + (size_t)row * D_MOD))[tid] = pk;
    if (outf) {
        float4 o = {y0, y1, y2, y3};
        ((float4*)(outf + (size_t)row * D_MOD))[tid] = o;
    }
}

// ---------------------------------------------------------------------------
// GEMM: C[M][N] = A[M][K](bf16) * B (given as BT[N][K] bf16) + bias
// optional ReLU, optional f32 residual add, write f32 and/or bf16.
// 128x128 tile, BK=64, 4 waves of 64x64, XOR-swizzled LDS.
// ---------------------------------------------------------------------------
template<bool RELU, bool RES, bool WF32, bool WBF16>
__global__ __launch_bounds__(256, 2)
void gemm_kernel(const __bf16* __restrict__ A, const __bf16* __restrict__ BT,
                 const float* __restrict__ bias, const float* __restrict__ res,
                 float* __restrict__ Cf, __bf16* __restrict__ Cb,
                 int M, int N, int K)
{
    __shared__ uint4 As[128 * 8];
    __shared__ uint4 Bs[128 * 8];
    const int tid = threadIdx.x;
    const int lane = tid & 63;
    const int w = tid >> 6;
    const int lrow = lane & 15;
    const int g = lane >> 4;
    const int bm = blockIdx.y * 128;
    const int bn = blockIdx.x * 128;
    const int wrow = (w >> 1) * 64;
    const int wcol = (w & 1) * 64;

    f32x4 acc[4][4];
    for (int m = 0; m < 4; m++)
        for (int n = 0; n < 4; n++)
            acc[m][n] = (f32x4){0.f, 0.f, 0.f, 0.f};

    const int srow = tid >> 3;  // 0..31
    const int sc = tid & 7;     // 16B chunk 0..7
    const __bf16* Ag = A + (size_t)(bm + srow) * K + sc * 8;
    const __bf16* Bg = BT + (size_t)(bn + srow) * K + sc * 8;
    const int swz = sc ^ (srow & 7);

    for (int kt = 0; kt < K; kt += 64) {
        uint4 ra[4], rb[4];
        for (int p = 0; p < 4; p++) {
            ra[p] = *(const uint4*)(Ag + (size_t)(p * 32) * K + kt);
            rb[p] = *(const uint4*)(Bg + (size_t)(p * 32) * K + kt);
        }
        __syncthreads();  // previous iteration's reads complete
        for (int p = 0; p < 4; p++) {
            int row = srow + p * 32;
            As[row * 8 + swz] = ra[p];
            Bs[row * 8 + swz] = rb[p];
        }
        __syncthreads();
        for (int kk = 0; kk < 2; kk++) {
            bf16x8 af[4], bfr[4];
            int c = kk * 4 + g;
            for (int m = 0; m < 4; m++) {
                int row = wrow + m * 16 + lrow;
                af[m] = __builtin_bit_cast(bf16x8, As[row * 8 + (c ^ (row & 7))]);
            }
            for (int n = 0; n < 4; n++) {
                int row = wcol + n * 16 + lrow;
                bfr[n] = __builtin_bit_cast(bf16x8, Bs[row * 8 + (c ^ (row & 7))]);
            }
            for (int m = 0; m < 4; m++)
                for (int n = 0; n < 4; n++)
                    acc[m][n] = MFMA16(af[m], bfr[n], acc[m][n]);
        }
    }

    for (int n = 0; n < 4; n++) {
        int col = bn + wcol + n * 16 + lrow;
        float bval = bias ? bias[col] : 0.f;
        for (int m = 0; m < 4; m++) {
            int row0 = bm + wrow + m * 16 + g * 4;
            for (int r = 0; r < 4; r++) {
                int row = row0 + r;
                float v = acc[m][n][r] + bval;
                if (RELU) v = fmaxf(v, 0.f);
                if (RES) v += res[(size_t)row * N + col];
                if (WF32) Cf[(size_t)row * N + col] = v;
                if (WBF16) Cb[(size_t)row * N + col] = (__bf16)v;
            }
        }
    }
}

// ---------------------------------------------------------------------------
// Attention: per block = (16 query rows, 1 head). Online softmax stats over
// QK^T, recompute pass writes normalized P (f32) to d_out + zero-fill, then
// PV via MFMA reading P back (L2-resident).
// ---------------------------------------------------------------------------
__global__ __launch_bounds__(256)
void attn_kernel(const __bf16* __restrict__ qb, const __bf16* __restrict__ kb,
                 const __bf16* __restrict__ vt, float* __restrict__ P,
                 __bf16* __restrict__ ctxb)
{
    const int tid = threadIdx.x;
    const int lane = tid & 63;
    const int w = tid >> 6;
    const int lrow = lane & 15;
    const int g = lane >> 4;
    const int r0 = blockIdx.x * 16;
    const int h = blockIdx.y;
    const int nkt = blockIdx.x + 1;    // 16-wide key tiles needed (causal)
    const int ncols = nkt * 16;
    const float scale = 0.125f;

    __shared__ float cm[4][16], cl[4][16], Mf[16], Li[16];

    // hoisted Q fragments (A operand: row = lane&15 = query, k contiguous)
    bf16x8 aq[2];
    for (int kk = 0; kk < 2; kk++)
        aq[kk] = *(const bf16x8*)(qb + (size_t)(r0 + lrow) * D_MOD + h * DK + kk * 32 + g * 8);

    float m4[4] = {-1e30f, -1e30f, -1e30f, -1e30f};
    float l4[4] = {0.f, 0.f, 0.f, 0.f};

    // ---- phase A: online (m,l) over key tiles (waves split tiles) ----
    for (int t = w; t < nkt; t += 4) {
        f32x4 acc = {0.f, 0.f, 0.f, 0.f};
        const __bf16* kp = kb + (size_t)(t * 16 + lrow) * D_MOD + h * DK + g * 8;
        acc = MFMA16(aq[0], *(const bf16x8*)kp, acc);
        acc = MFMA16(aq[1], *(const bf16x8*)(kp + 32), acc);
        int key = t * 16 + lrow;
        for (int r = 0; r < 4; r++) {
            int row = g * 4 + r;  // local query row of this C element
            float s = (key <= r0 + row) ? acc[r] * scale : -1e30f;
            if (s > m4[r]) { l4[r] *= __expf(m4[r] - s); m4[r] = s; }
            l4[r] += __expf(s - m4[r]);
        }
    }
    // reduce across the 16 lanes holding each row (lanes 16g..16g+15)
    for (int r = 0; r < 4; r++) {
        float m = m4[r], l = l4[r];
        for (int off = 1; off < 16; off <<= 1) {
            float om = __shfl_xor(m, off);
            float ol = __shfl_xor(l, off);
            float nm = fmaxf(m, om);
            l = l * __expf(m - nm) + ol * __expf(om - nm);
            m = nm;
        }
        m4[r] = m; l4[r] = l;
    }
    if (lrow == 0)
        for (int r = 0; r < 4; r++) { cm[w][g * 4 + r] = m4[r]; cl[w][g * 4 + r] = l4[r]; }
    __syncthreads();
    if (tid < 16) {
        float M = fmaxf(fmaxf(cm[0][tid], cm[1][tid]), fmaxf(cm[2][tid], cm[3][tid]));
        float L = 0.f;
        for (int i = 0; i < 4; i++) L += cl[i][tid] * __expf(cm[i][tid] - M);
        Mf[tid] = M;
        Li[tid] = 1.f / L;
    }
    __syncthreads();

    // ---- phase B1: recompute scores, write normalized P + zero fill ----
    const size_t Pbase = (size_t)h * S_LEN * S_LEN + (size_t)r0 * S_LEN;
    for (int t = w; t < nkt; t += 4) {
        f32x4 acc = {0.f, 0.f, 0.f, 0.f};
        const __bf16* kp = kb + (size_t)(t * 16 + lrow) * D_MOD + h * DK + g * 8;
        acc = MFMA16(aq[0], *(const bf16x8*)kp, acc);
        acc = MFMA16(aq[1], *(const bf16x8*)(kp + 32), acc);
        int key = t * 16 + lrow;
        for (int r = 0; r < 4; r++) {
            int row = g * 4 + r;
            float s = (key <= r0 + row) ? acc[r] * scale : -1e30f;
            float pv = __expf(s - Mf[row]) * Li[row];
            P[Pbase + (size_t)row * S_LEN + key] = pv;
        }
    }
    {   // zero the masked tail cols [ncols, 2048)
        int zc = (S_LEN - ncols) >> 2;  // float4 per row
        for (int idx = tid; idx < 16 * zc; idx += 256) {
            int row = idx / zc, c = idx - row * zc;
            float4 z = {0.f, 0.f, 0.f, 0.f};
            ((float4*)(P + Pbase + (size_t)row * S_LEN + ncols))[c] = z;
        }
    }
    __threadfence();
    __syncthreads();

    // ---- phase B2: ctx = P @ V  (wave w owns d-slice w*16..w*16+15) ----
    f32x4 accv = {0.f, 0.f, 0.f, 0.f};
    const int ksteps = (ncols + 31) / 32;
    const __bf16* vrow = vt + (size_t)(h * DK + w * 16 + lrow) * S_LEN;
    const float* prow = P + Pbase + (size_t)lrow * S_LEN + g * 8;
    for (int ks = 0; ks < ksteps; ks++) {
        float4 p0 = *(const float4*)(prow + ks * 32);
        float4 p1 = *(const float4*)(prow + ks * 32 + 4);
        bf16x8 ap;
        ap[0] = (__bf16)p0.x; ap[1] = (__bf16)p0.y; ap[2] = (__bf16)p0.z; ap[3] = (__bf16)p0.w;
        ap[4] = (__bf16)p1.x; ap[5] = (__bf16)p1.y; ap[6] = (__bf16)p1.z; ap[7] = (__bf16)p1.w;
        bf16x8 bv = *(const bf16x8*)(vrow + ks * 32 + g * 8);
        accv = MFMA16(ap, bv, accv);
    }
    for (int r = 0; r < 4; r++) {
        int row = r0 + g * 4 + r;
        ctxb[(size_t)row * D_MOD + h * DK + w * 16 + lrow] = (__bf16)accv[r];
    }
}

// ---------------------------------------------------------------------------
extern "C" void kernel_launch(void* const* d_in, const int* in_sizes, int n_in,
                              void* d_out, int out_size, void* d_ws, size_t ws_size,
                              hipStream_t stream)
{
    const float* x     = (const float*)d_in[0];
    const float* g1    = (const float*)d_in[1];
    const float* beta1 = (const float*)d_in[2];
    const float* W_in  = (const float*)d_in[3];
    const float* b_in  = (const float*)d_in[4];
    const float* Wq    = (const float*)d_in[5];
    const float* bq    = (const float*)d_in[6];
    const float* Wk    = (const float*)d_in[7];
    const float* bk    = (const float*)d_in[8];
    const float* Wv    = (const float*)d_in[9];
    const float* bv    = (const float*)d_in[10];
    const float* Wo    = (const float*)d_in[11];
    const float* bo    = (const float*)d_in[12];
    const float* W2    = (const float*)d_in[13];
    const float* b2    = (const float*)d_in[14];
    const float* g2    = (const float*)d_in[15];
    const float* beta2 = (const float*)d_in[16];
    const float* Wf1   = (const float*)d_in[17];
    const float* bf1   = (const float*)d_in[18];
    const float* Wf2   = (const float*)d_in[19];
    const float* bf2   = (const float*)d_in[20];

    float* outp = (float*)d_out;                    // [2048][1024]
    float* Pout = outp + (size_t)S_LEN * D_MOD;     // [16][2048][2048]

    char* p = (char*)d_ws;
    auto alloc = [&](size_t b) -> void* {
        void* r = (void*)p;
        p += (b + 255) & ~(size_t)255;
        return r;
    };
    __bf16* WinT  = (__bf16*)alloc((size_t)D_MOD * D_MOD * 2);
    __bf16* WqT   = (__bf16*)alloc((size_t)D_MOD * D_MOD * 2);
    __bf16* WkT   = (__bf16*)alloc((size_t)D_MOD * D_MOD * 2);
    __bf16* WvT   = (__bf16*)alloc((size_t)D_MOD * D_MOD * 2);
    __bf16* WoT   = (__bf16*)alloc((size_t)D_MOD * D_MOD * 2);
    __bf16* W2T   = (__bf16*)alloc((size_t)D_MOD * D_MOD * 2);
    __bf16* Wf1T  = (__bf16*)alloc((size_t)D_FF * D_MOD * 2);   // [4096][1024]
    __bf16* Wf2T  = (__bf16*)alloc((size_t)D_MOD * D_FF * 2);   // [1024][4096]
    __bf16* xn_b  = (__bf16*)alloc((size_t)S_LEN * D_MOD * 2);
    __bf16* h_b   = (__bf16*)alloc((size_t)S_LEN * D_MOD * 2);
    __bf16* q_b   = (__bf16*)alloc((size_t)S_LEN * D_MOD * 2);
    __bf16* k_b   = (__bf16*)alloc((size_t)S_LEN * D_MOD * 2);
    __bf16* v_b   = (__bf16*)alloc((size_t)S_LEN * D_MOD * 2);
    __bf16* VT    = (__bf16*)alloc((size_t)N_HEADS * DK * S_LEN * 2);
    __bf16* ctx_b = (__bf16*)alloc((size_t)S_LEN * D_MOD * 2);
    __bf16* mha_b = (__bf16*)alloc((size_t)S_LEN * D_MOD * 2);
    float* part1f = (float*)alloc((size_t)S_LEN * D_MOD * 4);
    float* norm2f = (float*)alloc((size_t)S_LEN * D_MOD * 4);
    __bf16* norm2b= (__bf16*)alloc((size_t)S_LEN * D_MOD * 2);
    __bf16* ff1_b = (__bf16*)alloc((size_t)S_LEN * D_FF * 2);

    dim3 blk(256);

    // weight transposes (f32 -> bf16, [K][N] -> [N][K])
    transpose_f32_bf16<<<dim3(32, 32), blk, 0, stream>>>(W_in, WinT, 1024, 1024);
    transpose_f32_bf16<<<dim3(32, 32), blk, 0, stream>>>(Wq, WqT, 1024, 1024);
    transpose_f32_bf16<<<dim3(32, 32), blk, 0, stream>>>(Wk, WkT, 1024, 1024);
    transpose_f32_bf16<<<dim3(32, 32), blk, 0, stream>>>(Wv, WvT, 1024, 1024);
    transpose_f32_bf16<<<dim3(32, 32), blk, 0, stream>>>(Wo, WoT, 1024, 1024);
    transpose_f32_bf16<<<dim3(32, 32), blk, 0, stream>>>(W2, W2T, 1024, 1024);
    transpose_f32_bf16<<<dim3(128, 32), blk, 0, stream>>>(Wf1, Wf1T, 1024, 4096);
    transpose_f32_bf16<<<dim3(32, 128), blk, 0, stream>>>(Wf2, Wf2T, 4096, 1024);

    // LN1
    ln_kernel<<<S_LEN, blk, 0, stream>>>(x, g1, beta1, xn_b, nullptr);

    // h = LN1(x) @ W_in + b_in
    gemm_kernel<false, false, false, true><<<dim3(8, 16), blk, 0, stream>>>(
        xn_b, WinT, b_in, nullptr, nullptr, h_b, 2048, 1024, 1024);

    // q, k, v
    gemm_kernel<false, false, false, true><<<dim3(8, 16), blk, 0, stream>>>(
        h_b, WqT, bq, nullptr, nullptr, q_b, 2048, 1024, 1024);
    gemm_kernel<false, false, false, true><<<dim3(8, 16), blk, 0, stream>>>(
        h_b, WkT, bk, nullptr, nullptr, k_b, 2048, 1024, 1024);
    gemm_kernel<false, false, false, true><<<dim3(8, 16), blk, 0, stream>>>(
        h_b, WvT, bv, nullptr, nullptr, v_b, 2048, 1024, 1024);

    // V -> VT per head
    vhead_transpose<<<dim3(64, 2, 16), blk, 0, stream>>>(v_b, VT);

    // attention: P (to d_out) + ctx
    attn_kernel<<<dim3(128, 16), blk, 0, stream>>>(q_b, k_b, VT, Pout, ctx_b);

    // mha = ctx @ Wo + bo
    gemm_kernel<false, false, false, true><<<dim3(8, 16), blk, 0, stream>>>(
        ctx_b, WoT, bo, nullptr, nullptr, mha_b, 2048, 1024, 1024);

    // part1 = x + mha @ W2 + b2   (f32)
    gemm_kernel<false, true, true, false><<<dim3(8, 16), blk, 0, stream>>>(
        mha_b, W2T, b2, x, part1f, nullptr, 2048, 1024, 1024);

    // LN2 (both f32 and bf16)
    ln_kernel<<<S_LEN, blk, 0, stream>>>(part1f, g2, beta2, norm2b, norm2f);

    // ff1 = relu(norm2 @ Wf1 + bf1)   (bf16)
    gemm_kernel<true, false, false, true><<<dim3(32, 16), blk, 0, stream>>>(
        norm2b, Wf1T, bf1, nullptr, nullptr, ff1_b, 2048, 4096, 1024);

    // out = norm2 + ff1 @ Wf2 + bf2   (f32 -> d_out)
    gemm_kernel<false, true, true, false><<<dim3(8, 16), blk, 0, stream>>>(
        ff1_b, Wf2T, bf2, norm2f, outp, nullptr, 2048, 1024, 4096);
}

// Round 2
// 761.330 us; speedup vs baseline: 1.5260x; 1.5260x over previous
//
#include <hip/hip_runtime.h>
#include <hip/hip_bf16.h>
#include <cstdint>

#define S_LEN 2048
#define D_MOD 1024
#define N_HEADS 16
#define DK 64
#define D_FF 4096

typedef __bf16 bf16x8 __attribute__((ext_vector_type(8)));
typedef float f32x4 __attribute__((ext_vector_type(4)));

#define MFMA16(a, b, c) __builtin_amdgcn_mfma_f32_16x16x32_bf16((a), (b), (c), 0, 0, 0)

// ---------------------------------------------------------------------------
// Weight transpose + f32->bf16:  W[K][N] f32 -> WT[N][K] bf16
// ---------------------------------------------------------------------------
__global__ __launch_bounds__(256)
void transpose_f32_bf16(const float* __restrict__ W, __bf16* __restrict__ WT, int K, int N)
{
    __shared__ float tile[32][33];
    int tx = threadIdx.x & 31, ty = threadIdx.x >> 5;
    int n0 = blockIdx.x * 32, k0 = blockIdx.y * 32;
    for (int i = 0; i < 4; i++)
        tile[ty + i * 8][tx] = W[(size_t)(k0 + ty + i * 8) * N + n0 + tx];
    __syncthreads();
    for (int i = 0; i < 4; i++)
        WT[(size_t)(n0 + ty + i * 8) * K + k0 + tx] = (__bf16)tile[tx][ty + i * 8];
}

// plain elementwise f32 -> bf16 (keeps layout)
__global__ __launch_bounds__(256)
void convert_f32_bf16(const float* __restrict__ W, __bf16* __restrict__ o)
{
    int i = (blockIdx.x * 256 + threadIdx.x);
    float4 v = ((const float4*)W)[i];
    unsigned short u0 = __builtin_bit_cast(unsigned short, (__bf16)v.x);
    unsigned short u1 = __builtin_bit_cast(unsigned short, (__bf16)v.y);
    unsigned short u2 = __builtin_bit_cast(unsigned short, (__bf16)v.z);
    unsigned short u3 = __builtin_bit_cast(unsigned short, (__bf16)v.w);
    uint2 pk;
    pk.x = (unsigned)u0 | ((unsigned)u1 << 16);
    pk.y = (unsigned)u2 | ((unsigned)u3 << 16);
    ((uint2*)o)[i] = pk;
}

// bqkv[n] = sum_k b_in[k]*W{q,k,v}[k][col] + b{q,k,v}[col]   (n in [0,3072))
__global__ __launch_bounds__(256)
void bias_qkv(const float* __restrict__ b_in,
              const float* __restrict__ Wq, const float* __restrict__ Wk, const float* __restrict__ Wv,
              const float* __restrict__ bq, const float* __restrict__ bk, const float* __restrict__ bv,
              float* __restrict__ o)
{
    int n = blockIdx.x * 256 + threadIdx.x;
    int sel = n >> 10, col = n & 1023;
    const float* W = sel == 0 ? Wq : (sel == 1 ? Wk : Wv);
    const float* bb = sel == 0 ? bq : (sel == 1 ? bk : bv);
    float s = bb[col];
    for (int k = 0; k < 1024; k++) s += b_in[k] * W[(size_t)k * 1024 + col];
    o[n] = s;
}

// bcomb[n] = sum_k bo[k]*W2[k][n] + b2[n]
__global__ __launch_bounds__(256)
void bias_comb(const float* __restrict__ bo, const float* __restrict__ W2,
               const float* __restrict__ b2, float* __restrict__ o)
{
    int n = blockIdx.x * 256 + threadIdx.x;
    float s = b2[n];
    for (int k = 0; k < 1024; k++) s += bo[k] * W2[(size_t)k * 1024 + n];
    o[n] = s;
}

// ---------------------------------------------------------------------------
// Per-head V transpose: qkv v-section [s][3072] -> VT[h][d][s] bf16
// ---------------------------------------------------------------------------
__global__ __launch_bounds__(256)
void vhead_transpose(const __bf16* __restrict__ v, __bf16* __restrict__ vt)
{
    __shared__ __bf16 tile[32][33];
    int tx = threadIdx.x & 31, ty = threadIdx.x >> 5;
    int s0 = blockIdx.x * 32;
    int d0 = blockIdx.y * 32;
    int h = blockIdx.z;
    for (int i = 0; i < 4; i++)
        tile[ty + i * 8][tx] = v[(size_t)(s0 + ty + i * 8) * 3072 + h * DK + d0 + tx];
    __syncthreads();
    for (int i = 0; i < 4; i++)
        vt[(size_t)(h * DK + d0 + ty + i * 8) * S_LEN + s0 + tx] = tile[tx][ty + i * 8];
}

// ---------------------------------------------------------------------------
// LayerNorm: y = g*(x-mean)/(std+eps)+b ; writes bf16 (and optional f32)
// ---------------------------------------------------------------------------
__global__ __launch_bounds__(256)
void ln_kernel(const float* __restrict__ x, const float* __restrict__ gamma,
               const float* __restrict__ beta, __bf16* __restrict__ outb,
               float* __restrict__ outf)
{
    int row = blockIdx.x;
    int tid = threadIdx.x;
    const float4 v = ((const float4*)(x + (size_t)row * D_MOD))[tid];
    float s = v.x + v.y + v.z + v.w;
    float sq = v.x * v.x + v.y * v.y + v.z * v.z + v.w * v.w;
    for (int off = 32; off; off >>= 1) {
        s += __shfl_down(s, off);
        sq += __shfl_down(sq, off);
    }
    __shared__ float red[8];
    int wid = tid >> 6;
    if ((tid & 63) == 0) { red[wid] = s; red[wid + 4] = sq; }
    __syncthreads();
    s = red[0] + red[1] + red[2] + red[3];
    sq = red[4] + red[5] + red[6] + red[7];
    float mean = s * (1.f / D_MOD);
    float var = sq * (1.f / D_MOD) - mean * mean;
    var = fmaxf(var, 0.f);
    float inv = 1.f / (sqrtf(var) + 1e-6f);
    float4 gv = ((const float4*)gamma)[tid];
    float4 bv = ((const float4*)beta)[tid];
    float y0 = gv.x * ((v.x - mean) * inv) + bv.x;
    float y1 = gv.y * ((v.y - mean) * inv) + bv.y;
    float y2 = gv.z * ((v.z - mean) * inv) + bv.z;
    float y3 = gv.w * ((v.w - mean) * inv) + bv.w;
    unsigned short u0 = __builtin_bit_cast(unsigned short, (__bf16)y0);
    unsigned short u1 = __builtin_bit_cast(unsigned short, (__bf16)y1);
    unsigned short u2 = __builtin_bit_cast(unsigned short, (__bf16)y2);
    unsigned short u3 = __builtin_bit_cast(unsigned short, (__bf16)y3);
    uint2 pk;
    pk.x = (unsigned)u0 | ((unsigned)u1 << 16);
    pk.y = (unsigned)u2 | ((unsigned)u3 << 16);
    ((uint2*)(outb + (size_t)row * D_MOD))[tid] = pk;
    if (outf) {
        float4 o = {y0, y1, y2, y3};
        ((float4*)(outf + (size_t)row * D_MOD))[tid] = o;
    }
}

// ---------------------------------------------------------------------------
// GEMM: C[M][N] = A[M][K](bf16) * BT[N][K](bf16) + bias; 128xBN tile, BK=64
// ---------------------------------------------------------------------------
template<int BN, bool RELU, bool RES, bool WF32, bool WBF16>
__global__ __launch_bounds__(256, 2)
void gemm_kernel(const __bf16* __restrict__ A, const __bf16* __restrict__ BT,
                 const float* __restrict__ bias, const float* __restrict__ res,
                 float* __restrict__ Cf, __bf16* __restrict__ Cb,
                 int M, int N, int K)
{
    constexpr int NFRAG = BN / 32;   // wave col fragments (BN/2 cols per wave)
    __shared__ uint4 As[128 * 8];
    __shared__ uint4 Bs[BN * 8];
    const int tid = threadIdx.x;
    const int lane = tid & 63;
    const int w = tid >> 6;
    const int lrow = lane & 15;
    const int g = lane >> 4;
    const int bm = blockIdx.y * 128;
    const int bn = blockIdx.x * BN;
    const int wrow = (w >> 1) * 64;
    const int wcol = (w & 1) * (BN / 2);

    f32x4 acc[4][NFRAG];
    for (int m = 0; m < 4; m++)
        for (int n = 0; n < NFRAG; n++)
            acc[m][n] = (f32x4){0.f, 0.f, 0.f, 0.f};

    const int srow = tid >> 3;
    const int sc = tid & 7;
    const __bf16* Ag = A + (size_t)(bm + srow) * K + sc * 8;
    const __bf16* Bg = BT + (size_t)(bn + srow) * K + sc * 8;
    const int swz = sc ^ (srow & 7);

    for (int kt = 0; kt < K; kt += 64) {
        uint4 ra[4], rb[NFRAG];
        for (int p = 0; p < 4; p++)
            ra[p] = *(const uint4*)(Ag + (size_t)(p * 32) * K + kt);
        for (int p = 0; p < NFRAG; p++)
            rb[p] = *(const uint4*)(Bg + (size_t)(p * 32) * K + kt);
        __syncthreads();
        for (int p = 0; p < 4; p++)
            As[(srow + p * 32) * 8 + swz] = ra[p];
        for (int p = 0; p < NFRAG; p++)
            Bs[(srow + p * 32) * 8 + swz] = rb[p];
        __syncthreads();
        for (int kk = 0; kk < 2; kk++) {
            bf16x8 af[4], bfr[NFRAG];
            int c = kk * 4 + g;
            for (int m = 0; m < 4; m++) {
                int row = wrow + m * 16 + lrow;
                af[m] = __builtin_bit_cast(bf16x8, As[row * 8 + (c ^ (row & 7))]);
            }
            for (int n = 0; n < NFRAG; n++) {
                int row = wcol + n * 16 + lrow;
                bfr[n] = __builtin_bit_cast(bf16x8, Bs[row * 8 + (c ^ (row & 7))]);
            }
            for (int m = 0; m < 4; m++)
                for (int n = 0; n < NFRAG; n++)
                    acc[m][n] = MFMA16(af[m], bfr[n], acc[m][n]);
        }
    }

    for (int n = 0; n < NFRAG; n++) {
        int col = bn + wcol + n * 16 + lrow;
        float bval = bias ? bias[col] : 0.f;
        for (int m = 0; m < 4; m++) {
            int row0 = bm + wrow + m * 16 + g * 4;
            for (int r = 0; r < 4; r++) {
                int row = row0 + r;
                float v = acc[m][n][r] + bval;
                if (RELU) v = fmaxf(v, 0.f);
                if (RES) v += res[(size_t)row * N + col];
                if (WF32) Cf[(size_t)row * N + col] = v;
                if (WBF16) Cb[(size_t)row * N + col] = (__bf16)v;
            }
        }
    }
}

// ---------------------------------------------------------------------------
// attn_stats: per (64-row qtile, head) block; wave owns 16 rows.
// Writes final row max M and 1/L to Mbuf/Lbuf [h][2048].
// ---------------------------------------------------------------------------
__global__ __launch_bounds__(256)
void attn_stats(const __bf16* __restrict__ qkv, float* __restrict__ Mbuf,
                float* __restrict__ Lbuf)
{
    const int tid = threadIdx.x;
    const int lane = tid & 63;
    const int w = tid >> 6;
    const int lrow = lane & 15;
    const int g = lane >> 4;
    const int qt = (int)gridDim.x - 1 - (int)blockIdx.x;   // heavy tiles first
    const int h = blockIdx.y;
    const int r0 = qt * 64 + w * 16;
    const float scale = 0.125f;

    const __bf16* qb = qkv;
    const __bf16* kb = qkv + 1024;
    bf16x8 aq0 = *(const bf16x8*)(qb + (size_t)(r0 + lrow) * 3072 + h * DK + g * 8);
    bf16x8 aq1 = *(const bf16x8*)(qb + (size_t)(r0 + lrow) * 3072 + h * DK + 32 + g * 8);

    float m4[4] = {-1e30f, -1e30f, -1e30f, -1e30f};
    float l4[4] = {0.f, 0.f, 0.f, 0.f};
    const int nkt = qt * 4 + w + 1;
    const __bf16* kp = kb + h * DK + g * 8;

    bf16x8 k0 = *(const bf16x8*)(kp + (size_t)lrow * 3072);
    bf16x8 k1 = *(const bf16x8*)(kp + (size_t)lrow * 3072 + 32);
    for (int t = 0; t < nkt; t++) {
        bf16x8 n0 = k0, n1 = k1;
        if (t + 1 < nkt) {
            n0 = *(const bf16x8*)(kp + (size_t)((t + 1) * 16 + lrow) * 3072);
            n1 = *(const bf16x8*)(kp + (size_t)((t + 1) * 16 + lrow) * 3072 + 32);
        }
        f32x4 acc = {0.f, 0.f, 0.f, 0.f};
        acc = MFMA16(aq0, k0, acc);
        acc = MFMA16(aq1, k1, acc);
        int key = t * 16 + lrow;
        for (int r = 0; r < 4; r++) {
            int qrow = r0 + g * 4 + r;
            float s = (key <= qrow) ? acc[r] * scale : -1e30f;
            float nm = fmaxf(m4[r], s);
            l4[r] = l4[r] * __expf(m4[r] - nm) + __expf(s - nm);
            m4[r] = nm;
        }
        k0 = n0; k1 = n1;
    }
    for (int r = 0; r < 4; r++) {
        float m = m4[r], l = l4[r];
        for (int off = 1; off < 16; off <<= 1) {
            float om = __shfl_xor(m, off);
            float ol = __shfl_xor(l, off);
            float nm = fmaxf(m, om);
            l = l * __expf(m - nm) + ol * __expf(om - nm);
            m = nm;
        }
        m4[r] = m; l4[r] = l;
    }
    if (lrow == 0) {
        for (int r = 0; r < 4; r++) {
            int row = r0 + g * 4 + r;
            Mbuf[h * S_LEN + row] = m4[r];
            Lbuf[h * S_LEN + row] = 1.f / l4[r];
        }
    }
}

// ---------------------------------------------------------------------------
// attn_pwrite: one block per 128x128 S tile per head; writes normalized P f32.
// kt > qt tiles: pure zero-fill.
// ---------------------------------------------------------------------------
__global__ __launch_bounds__(256, 2)
void attn_pwrite(const __bf16* __restrict__ qkv, const float* __restrict__ Mbuf,
                 const float* __restrict__ Lbuf, float* __restrict__ P)
{
    const int tid = threadIdx.x;
    const int kt = blockIdx.x, qt = blockIdx.y, h = blockIdx.z;
    const size_t Pb = (size_t)h * S_LEN * S_LEN;

    if (kt > qt) {
        float4 z = {0.f, 0.f, 0.f, 0.f};
        for (int i = tid; i < 128 * 32; i += 256) {
            int row = i >> 5, c = i & 31;
            ((float4*)(P + Pb + (size_t)(qt * 128 + row) * S_LEN + kt * 128))[c] = z;
        }
        return;
    }

    __shared__ uint4 Qs[128 * 8];
    __shared__ uint4 Ks[128 * 8];
    const int lane = tid & 63;
    const int w = tid >> 6;
    const int lrow = lane & 15;
    const int g = lane >> 4;
    const int srow = tid >> 3;
    const int sc = tid & 7;
    const int swz = sc ^ (srow & 7);
    const __bf16* qg = qkv + (size_t)(qt * 128 + srow) * 3072 + h * DK + sc * 8;
    const __bf16* kg = qkv + 1024 + (size_t)(kt * 128 + srow) * 3072 + h * DK + sc * 8;
    for (int p = 0; p < 4; p++) {
        Qs[(srow + p * 32) * 8 + swz] = *(const uint4*)(qg + (size_t)(p * 32) * 3072);
        Ks[(srow + p * 32) * 8 + swz] = *(const uint4*)(kg + (size_t)(p * 32) * 3072);
    }
    __syncthreads();

    const int wrow = (w >> 1) * 64;   // q
    const int wcol = (w & 1) * 64;    // k
    f32x4 acc[4][4];
    for (int m = 0; m < 4; m++)
        for (int n = 0; n < 4; n++)
            acc[m][n] = (f32x4){0.f, 0.f, 0.f, 0.f};
    for (int kk = 0; kk < 2; kk++) {
        bf16x8 af[4], bfr[4];
        int c = kk * 4 + g;
        for (int m = 0; m < 4; m++) {
            int row = wrow + m * 16 + lrow;
            af[m] = __builtin_bit_cast(bf16x8, Qs[row * 8 + (c ^ (row & 7))]);
        }
        for (int n = 0; n < 4; n++) {
            int row = wcol + n * 16 + lrow;
            bfr[n] = __builtin_bit_cast(bf16x8, Ks[row * 8 + (c ^ (row & 7))]);
        }
        for (int m = 0; m < 4; m++)
            for (int n = 0; n < 4; n++)
                acc[m][n] = MFMA16(af[m], bfr[n], acc[m][n]);
    }

    const float scale = 0.125f;
    for (int m = 0; m < 4; m++) {
        int qa0 = qt * 128 + wrow + m * 16 + g * 4;
        float Mv[4], Lv[4];
        for (int r = 0; r < 4; r++) {
            Mv[r] = Mbuf[h * S_LEN + qa0 + r];
            Lv[r] = Lbuf[h * S_LEN + qa0 + r];
        }
        for (int n = 0; n < 4; n++) {
            int kc = kt * 128 + wcol + n * 16 + lrow;
            for (int r = 0; r < 4; r++) {
                int qa = qa0 + r;
                float s = acc[m][n][r] * scale;
                float pv = (kc <= qa) ? __expf(s - Mv[r]) * Lv[r] : 0.f;
                P[Pb + (size_t)qa * S_LEN + kc] = pv;
            }
        }
    }
}

// ---------------------------------------------------------------------------
// attn_pv: ctx = P @ V. Block = (16 q-rows, head); 4 waves split K; LDS reduce.
// ---------------------------------------------------------------------------
__global__ __launch_bounds__(256)
void attn_pv(const float* __restrict__ P, const __bf16* __restrict__ vt,
             __bf16* __restrict__ ctx)
{
    const int tid = threadIdx.x;
    const int lane = tid & 63;
    const int w = tid >> 6;
    const int lrow = lane & 15;
    const int g = lane >> 4;
    const int qt = (int)gridDim.x - 1 - (int)blockIdx.x;  // heavy first
    const int h = blockIdx.y;
    const int ncols = qt * 16 + 16;
    const int ksteps = (ncols + 31) >> 5;

    f32x4 acc[4];
    for (int n = 0; n < 4; n++) acc[n] = (f32x4){0.f, 0.f, 0.f, 0.f};

    const float* prow = P + (size_t)h * S_LEN * S_LEN + (size_t)(qt * 16 + lrow) * S_LEN + g * 8;
    const __bf16* vbase = vt + (size_t)(h * DK) * S_LEN;

    for (int ks = w; ks < ksteps; ks += 4) {
        float4 p0 = *(const float4*)(prow + ks * 32);
        float4 p1 = *(const float4*)(prow + ks * 32 + 4);
        bf16x8 ap;
        ap[0] = (__bf16)p0.x; ap[1] = (__bf16)p0.y; ap[2] = (__bf16)p0.z; ap[3] = (__bf16)p0.w;
        ap[4] = (__bf16)p1.x; ap[5] = (__bf16)p1.y; ap[6] = (__bf16)p1.z; ap[7] = (__bf16)p1.w;
        for (int n = 0; n < 4; n++) {
            bf16x8 bv = *(const bf16x8*)(vbase + (size_t)(n * 16 + lrow) * S_LEN + ks * 32 + g * 8);
            acc[n] = MFMA16(ap, bv, acc[n]);
        }
    }

    __shared__ float red[4][16][64];
    for (int n = 0; n < 4; n++)
        for (int r = 0; r < 4; r++)
            red[w][g * 4 + r][n * 16 + lrow] = acc[n][r];
    __syncthreads();
    for (int i = tid; i < 1024; i += 256) {
        int row = i >> 6, col = i & 63;
        float sum = red[0][row][col] + red[1][row][col] + red[2][row][col] + red[3][row][col];
        ctx[(size_t)(qt * 16 + row) * D_MOD + h * DK + col] = (__bf16)sum;
    }
}

// ---------------------------------------------------------------------------
extern "C" void kernel_launch(void* const* d_in, const int* in_sizes, int n_in,
                              void* d_out, int out_size, void* d_ws, size_t ws_size,
                              hipStream_t stream)
{
    const float* x     = (const float*)d_in[0];
    const float* g1    = (const float*)d_in[1];
    const float* beta1 = (const float*)d_in[2];
    const float* W_in  = (const float*)d_in[3];
    const float* b_in  = (const float*)d_in[4];
    const float* Wq    = (const float*)d_in[5];
    const float* bq    = (const float*)d_in[6];
    const float* Wk    = (const float*)d_in[7];
    const float* bk    = (const float*)d_in[8];
    const float* Wv    = (const float*)d_in[9];
    const float* bv    = (const float*)d_in[10];
    const float* Wo    = (const float*)d_in[11];
    const float* bo    = (const float*)d_in[12];
    const float* W2    = (const float*)d_in[13];
    const float* b2    = (const float*)d_in[14];
    const float* g2    = (const float*)d_in[15];
    const float* beta2 = (const float*)d_in[16];
    const float* Wf1   = (const float*)d_in[17];
    const float* bf1   = (const float*)d_in[18];
    const float* Wf2   = (const float*)d_in[19];
    const float* bf2   = (const float*)d_in[20];

    float* outp = (float*)d_out;                    // [2048][1024]
    float* Pout = outp + (size_t)S_LEN * D_MOD;     // [16][2048][2048]

    char* p = (char*)d_ws;
    auto alloc = [&](size_t b) -> void* {
        void* r = (void*)p;
        p += (b + 255) & ~(size_t)255;
        return r;
    };
    __bf16* WqkvT    = (__bf16*)alloc((size_t)3072 * 1024 * 2);  // [Wq^T;Wk^T;Wv^T]
    __bf16* W2T      = (__bf16*)alloc((size_t)1024 * 1024 * 2);
    __bf16* Wf1T     = (__bf16*)alloc((size_t)D_FF * D_MOD * 2);
    __bf16* Wf2T     = (__bf16*)alloc((size_t)D_MOD * D_FF * 2);
    __bf16* WqkvCT   = (__bf16*)alloc((size_t)3072 * 1024 * 2);  // (Win·Wqkv)^T
    __bf16* WcombT   = (__bf16*)alloc((size_t)1024 * 1024 * 2);  // (Wo·W2)^T
    float*  bqkv     = (float*)alloc((size_t)3072 * 4);
    float*  bcomb    = (float*)alloc((size_t)1024 * 4);
    __bf16* xn_b     = (__bf16*)alloc((size_t)S_LEN * D_MOD * 2);
    __bf16* qkv_b    = (__bf16*)alloc((size_t)S_LEN * 3072 * 2);
    __bf16* VT       = (__bf16*)alloc((size_t)N_HEADS * DK * S_LEN * 2);
    __bf16* ctx_b    = (__bf16*)alloc((size_t)S_LEN * D_MOD * 2);
    float*  part1f   = (float*)alloc((size_t)S_LEN * D_MOD * 4);
    float*  norm2f   = (float*)alloc((size_t)S_LEN * D_MOD * 4);
    __bf16* norm2b   = (__bf16*)alloc((size_t)S_LEN * D_MOD * 2);
    __bf16* ff1_b    = (__bf16*)alloc((size_t)S_LEN * D_FF * 2);
    float*  Mbuf     = (float*)alloc((size_t)N_HEADS * S_LEN * 4);
    float*  Lbuf     = (float*)alloc((size_t)N_HEADS * S_LEN * 4);
    // aliases: weight staging only needed before part1f/norm2f are written
    __bf16* Win_b = (__bf16*)part1f;   // plain bf16 copy of W_in [1024][1024]
    __bf16* Wo_b  = (__bf16*)norm2f;   // plain bf16 copy of Wo   [1024][1024]

    dim3 blk(256);

    // --- weight prep ---
    transpose_f32_bf16<<<dim3(32, 32), blk, 0, stream>>>(Wq, WqkvT, 1024, 1024);
    transpose_f32_bf16<<<dim3(32, 32), blk, 0, stream>>>(Wk, WqkvT + 1024 * 1024, 1024, 1024);
    transpose_f32_bf16<<<dim3(32, 32), blk, 0, stream>>>(Wv, WqkvT + 2 * 1024 * 1024, 1024, 1024);
    transpose_f32_bf16<<<dim3(32, 32), blk, 0, stream>>>(W2, W2T, 1024, 1024);
    transpose_f32_bf16<<<dim3(128, 32), blk, 0, stream>>>(Wf1, Wf1T, 1024, 4096);
    transpose_f32_bf16<<<dim3(32, 128), blk, 0, stream>>>(Wf2, Wf2T, 4096, 1024);
    convert_f32_bf16<<<dim3(1024), blk, 0, stream>>>(W_in, Win_b);
    convert_f32_bf16<<<dim3(1024), blk, 0, stream>>>(Wo, Wo_b);
    bias_qkv<<<dim3(12), blk, 0, stream>>>(b_in, Wq, Wk, Wv, bq, bk, bv, bqkv);
    bias_comb<<<dim3(4), blk, 0, stream>>>(bo, W2, b2, bcomb);

    // WqkvCT[n][j] = sum_k WqkvT[n][k] * Win[j][k]  -> (Win·Wqkv)^T
    gemm_kernel<64, false, false, false, true><<<dim3(16, 24), blk, 0, stream>>>(
        WqkvT, Win_b, nullptr, nullptr, nullptr, WqkvCT, 3072, 1024, 1024);
    // WcombT[n][j] = sum_k W2T[n][k] * Wo[j][k]    -> (Wo·W2)^T
    gemm_kernel<64, false, false, false, true><<<dim3(16, 8), blk, 0, stream>>>(
        W2T, Wo_b, nullptr, nullptr, nullptr, WcombT, 1024, 1024, 1024);

    // --- forward ---
    ln_kernel<<<S_LEN, blk, 0, stream>>>(x, g1, beta1, xn_b, nullptr);

    // qkv = LN1(x) @ (Win·Wqkv) + bqkv    [2048][3072]
    gemm_kernel<128, false, false, false, true><<<dim3(24, 16), blk, 0, stream>>>(
        xn_b, WqkvCT, bqkv, nullptr, nullptr, qkv_b, 2048, 3072, 1024);

    vhead_transpose<<<dim3(64, 2, 16), blk, 0, stream>>>(qkv_b + 2048, VT);

    attn_stats<<<dim3(32, 16), blk, 0, stream>>>(qkv_b, Mbuf, Lbuf);
    attn_pwrite<<<dim3(16, 16, 16), blk, 0, stream>>>(qkv_b, Mbuf, Lbuf, Pout);
    attn_pv<<<dim3(128, 16), blk, 0, stream>>>(Pout, VT, ctx_b);

    // part1 = x + ctx @ (Wo·W2) + bcomb   (f32)
    gemm_kernel<64, false, true, true, false><<<dim3(16, 16), blk, 0, stream>>>(
        ctx_b, WcombT, bcomb, x, part1f, nullptr, 2048, 1024, 1024);

    ln_kernel<<<S_LEN, blk, 0, stream>>>(part1f, g2, beta2, norm2b, norm2f);

    // ff1 = relu(norm2 @ Wf1 + bf1)
    gemm_kernel<128, true, false, false, true><<<dim3(32, 16), blk, 0, stream>>>(
        norm2b, Wf1T, bf1, nullptr, nullptr, ff1_b, 2048, 4096, 1024);

    // out = norm2 + ff1 @ Wf2 + bf2  -> d_out
    gemm_kernel<64, false, true, true, false><<<dim3(16, 16), blk, 0, stream>>>(
        ff1_b, Wf2T, bf2, norm2f, outp, nullptr, 2048, 1024, 4096);
}

// Round 3
// 704.360 us; speedup vs baseline: 1.6495x; 1.0809x over previous
//
#include <hip/hip_runtime.h>
#include <hip/hip_bf16.h>
#include <cstdint>

#define S_LEN 2048
#define D_MOD 1024
#define N_HEADS 16
#define DK 64
#define D_FF 4096

typedef __bf16 bf16x8 __attribute__((ext_vector_type(8)));
typedef float f32x4 __attribute__((ext_vector_type(4)));

#define MFMA16(a, b, c) __builtin_amdgcn_mfma_f32_16x16x32_bf16((a), (b), (c), 0, 0, 0)

__device__ inline unsigned pack_bf16x2(float a, float b)
{
    unsigned short ua = __builtin_bit_cast(unsigned short, (__bf16)a);
    unsigned short ub = __builtin_bit_cast(unsigned short, (__bf16)b);
    return (unsigned)ua | ((unsigned)ub << 16);
}

// ---------------------------------------------------------------------------
// Weight transpose + f32->bf16:  W[K][N] f32 -> WT[N][K] bf16
// ---------------------------------------------------------------------------
__global__ __launch_bounds__(256)
void transpose_f32_bf16(const float* __restrict__ W, __bf16* __restrict__ WT, int K, int N)
{
    __shared__ float tile[32][33];
    int tx = threadIdx.x & 31, ty = threadIdx.x >> 5;
    int n0 = blockIdx.x * 32, k0 = blockIdx.y * 32;
    for (int i = 0; i < 4; i++)
        tile[ty + i * 8][tx] = W[(size_t)(k0 + ty + i * 8) * N + n0 + tx];
    __syncthreads();
    for (int i = 0; i < 4; i++)
        WT[(size_t)(n0 + ty + i * 8) * K + k0 + tx] = (__bf16)tile[tx][ty + i * 8];
}

// plain elementwise f32 -> bf16 (keeps layout)
__global__ __launch_bounds__(256)
void convert_f32_bf16(const float* __restrict__ W, __bf16* __restrict__ o)
{
    int i = (blockIdx.x * 256 + threadIdx.x);
    float4 v = ((const float4*)W)[i];
    uint2 pk;
    pk.x = pack_bf16x2(v.x, v.y);
    pk.y = pack_bf16x2(v.z, v.w);
    ((uint2*)o)[i] = pk;
}

// ---------------------------------------------------------------------------
// bias matvecs, two-stage parallel reduce.
// outputs n in [0,4096): [0,3072) -> bqkv (b_in @ Wq|Wk|Wv + bq|bk|bv)
//                        [3072,4096) -> bcomb (bo @ W2 + b2)
// ---------------------------------------------------------------------------
__global__ __launch_bounds__(256)
void bias_stage1(const float* __restrict__ b_in, const float* __restrict__ bo,
                 const float* __restrict__ Wq, const float* __restrict__ Wk,
                 const float* __restrict__ Wv, const float* __restrict__ W2,
                 float* __restrict__ part)
{
    int n = blockIdx.x * 256 + threadIdx.x;
    int kc = blockIdx.y;
    int sel = n >> 10, col = n & 1023;
    const float* W = sel == 0 ? Wq : (sel == 1 ? Wk : (sel == 2 ? Wv : W2));
    const float* src = sel < 3 ? b_in : bo;
    float s = 0.f;
    for (int k = kc * 128; k < kc * 128 + 128; k++)
        s += src[k] * W[(size_t)k * 1024 + col];
    part[kc * 4096 + n] = s;
}

__global__ __launch_bounds__(256)
void bias_stage2(const float* __restrict__ part,
                 const float* __restrict__ bq, const float* __restrict__ bk,
                 const float* __restrict__ bv, const float* __restrict__ b2,
                 float* __restrict__ bqkv, float* __restrict__ bcomb)
{
    int n = blockIdx.x * 256 + threadIdx.x;
    int sel = n >> 10, col = n & 1023;
    float s = sel == 0 ? bq[col] : (sel == 1 ? bk[col] : (sel == 2 ? bv[col] : b2[col]));
    for (int kc = 0; kc < 8; kc++) s += part[kc * 4096 + n];
    if (n < 3072) bqkv[n] = s; else bcomb[col] = s;
}

// ---------------------------------------------------------------------------
// Per-head V transpose: qkv v-section [s][3072] -> VT[h][d][s] bf16
// ---------------------------------------------------------------------------
__global__ __launch_bounds__(256)
void vhead_transpose(const __bf16* __restrict__ v, __bf16* __restrict__ vt)
{
    __shared__ __bf16 tile[32][33];
    int tx = threadIdx.x & 31, ty = threadIdx.x >> 5;
    int s0 = blockIdx.x * 32;
    int d0 = blockIdx.y * 32;
    int h = blockIdx.z;
    for (int i = 0; i < 4; i++)
        tile[ty + i * 8][tx] = v[(size_t)(s0 + ty + i * 8) * 3072 + h * DK + d0 + tx];
    __syncthreads();
    for (int i = 0; i < 4; i++)
        vt[(size_t)(h * DK + d0 + ty + i * 8) * S_LEN + s0 + tx] = tile[tx][ty + i * 8];
}

// ---------------------------------------------------------------------------
// LayerNorm
// ---------------------------------------------------------------------------
__global__ __launch_bounds__(256)
void ln_kernel(const float* __restrict__ x, const float* __restrict__ gamma,
               const float* __restrict__ beta, __bf16* __restrict__ outb,
               float* __restrict__ outf)
{
    int row = blockIdx.x;
    int tid = threadIdx.x;
    const float4 v = ((const float4*)(x + (size_t)row * D_MOD))[tid];
    float s = v.x + v.y + v.z + v.w;
    float sq = v.x * v.x + v.y * v.y + v.z * v.z + v.w * v.w;
    for (int off = 32; off; off >>= 1) {
        s += __shfl_down(s, off);
        sq += __shfl_down(sq, off);
    }
    __shared__ float red[8];
    int wid = tid >> 6;
    if ((tid & 63) == 0) { red[wid] = s; red[wid + 4] = sq; }
    __syncthreads();
    s = red[0] + red[1] + red[2] + red[3];
    sq = red[4] + red[5] + red[6] + red[7];
    float mean = s * (1.f / D_MOD);
    float var = sq * (1.f / D_MOD) - mean * mean;
    var = fmaxf(var, 0.f);
    float inv = 1.f / (sqrtf(var) + 1e-6f);
    float4 gv = ((const float4*)gamma)[tid];
    float4 bv = ((const float4*)beta)[tid];
    float y0 = gv.x * ((v.x - mean) * inv) + bv.x;
    float y1 = gv.y * ((v.y - mean) * inv) + bv.y;
    float y2 = gv.z * ((v.z - mean) * inv) + bv.z;
    float y3 = gv.w * ((v.w - mean) * inv) + bv.w;
    uint2 pk;
    pk.x = pack_bf16x2(y0, y1);
    pk.y = pack_bf16x2(y2, y3);
    ((uint2*)(outb + (size_t)row * D_MOD))[tid] = pk;
    if (outf) {
        float4 o = {y0, y1, y2, y3};
        ((float4*)(outf + (size_t)row * D_MOD))[tid] = o;
    }
}

// ---------------------------------------------------------------------------
// GEMM: C[M][N] = A[M][K](bf16) * BT[N][K](bf16) + bias; 128xBN tile, BK=64
// ---------------------------------------------------------------------------
template<int BN, bool RELU, bool RES, bool WF32, bool WBF16>
__global__ __launch_bounds__(256, 2)
void gemm_kernel(const __bf16* __restrict__ A, const __bf16* __restrict__ BT,
                 const float* __restrict__ bias, const float* __restrict__ res,
                 float* __restrict__ Cf, __bf16* __restrict__ Cb,
                 int M, int N, int K)
{
    constexpr int NFRAG = BN / 32;
    __shared__ uint4 As[128 * 8];
    __shared__ uint4 Bs[BN * 8];
    const int tid = threadIdx.x;
    const int lane = tid & 63;
    const int w = tid >> 6;
    const int lrow = lane & 15;
    const int g = lane >> 4;
    const int bm = blockIdx.y * 128;
    const int bn = blockIdx.x * BN;
    const int wrow = (w >> 1) * 64;
    const int wcol = (w & 1) * (BN / 2);

    f32x4 acc[4][NFRAG];
    for (int m = 0; m < 4; m++)
        for (int n = 0; n < NFRAG; n++)
            acc[m][n] = (f32x4){0.f, 0.f, 0.f, 0.f};

    const int srow = tid >> 3;
    const int sc = tid & 7;
    const __bf16* Ag = A + (size_t)(bm + srow) * K + sc * 8;
    const __bf16* Bg = BT + (size_t)(bn + srow) * K + sc * 8;
    const int swz = sc ^ (srow & 7);

    for (int kt = 0; kt < K; kt += 64) {
        uint4 ra[4], rb[NFRAG];
        for (int p = 0; p < 4; p++)
            ra[p] = *(const uint4*)(Ag + (size_t)(p * 32) * K + kt);
        for (int p = 0; p < NFRAG; p++)
            rb[p] = *(const uint4*)(Bg + (size_t)(p * 32) * K + kt);
        __syncthreads();
        for (int p = 0; p < 4; p++)
            As[(srow + p * 32) * 8 + swz] = ra[p];
        for (int p = 0; p < NFRAG; p++)
            Bs[(srow + p * 32) * 8 + swz] = rb[p];
        __syncthreads();
        for (int kk = 0; kk < 2; kk++) {
            bf16x8 af[4], bfr[NFRAG];
            int c = kk * 4 + g;
            for (int m = 0; m < 4; m++) {
                int row = wrow + m * 16 + lrow;
                af[m] = __builtin_bit_cast(bf16x8, As[row * 8 + (c ^ (row & 7))]);
            }
            for (int n = 0; n < NFRAG; n++) {
                int row = wcol + n * 16 + lrow;
                bfr[n] = __builtin_bit_cast(bf16x8, Bs[row * 8 + (c ^ (row & 7))]);
            }
            for (int m = 0; m < 4; m++)
                for (int n = 0; n < NFRAG; n++)
                    acc[m][n] = MFMA16(af[m], bfr[n], acc[m][n]);
        }
    }

    for (int n = 0; n < NFRAG; n++) {
        int col = bn + wcol + n * 16 + lrow;
        float bval = bias ? bias[col] : 0.f;
        for (int m = 0; m < 4; m++) {
            int row0 = bm + wrow + m * 16 + g * 4;
            for (int r = 0; r < 4; r++) {
                int row = row0 + r;
                float v = acc[m][n][r] + bval;
                if (RELU) v = fmaxf(v, 0.f);
                if (RES) v += res[(size_t)row * N + col];
                if (WF32) Cf[(size_t)row * N + col] = v;
                if (WBF16) Cb[(size_t)row * N + col] = (__bf16)v;
            }
        }
    }
}

// ---------------------------------------------------------------------------
// attn_stats: per (64-row qtile, head); writes off = -M*log2e - log2(L)
// ---------------------------------------------------------------------------
__global__ __launch_bounds__(256)
void attn_stats(const __bf16* __restrict__ qkv, float* __restrict__ Obuf)
{
    const int tid = threadIdx.x;
    const int lane = tid & 63;
    const int w = tid >> 6;
    const int lrow = lane & 15;
    const int g = lane >> 4;
    const int qt = (int)gridDim.x - 1 - (int)blockIdx.x;   // heavy first
    const int h = blockIdx.y;
    const int r0 = qt * 64 + w * 16;
    const float scale = 0.125f;

    const __bf16* qb = qkv;
    const __bf16* kb = qkv + 1024;
    bf16x8 aq0 = *(const bf16x8*)(qb + (size_t)(r0 + lrow) * 3072 + h * DK + g * 8);
    bf16x8 aq1 = *(const bf16x8*)(qb + (size_t)(r0 + lrow) * 3072 + h * DK + 32 + g * 8);

    float m4[4] = {-1e30f, -1e30f, -1e30f, -1e30f};
    float l4[4] = {0.f, 0.f, 0.f, 0.f};
    const int nkt = qt * 4 + w + 1;
    const __bf16* kp = kb + h * DK + g * 8;

    bf16x8 k0 = *(const bf16x8*)(kp + (size_t)lrow * 3072);
    bf16x8 k1 = *(const bf16x8*)(kp + (size_t)lrow * 3072 + 32);
    for (int t = 0; t < nkt; t++) {
        bf16x8 n0 = k0, n1 = k1;
        if (t + 1 < nkt) {
            n0 = *(const bf16x8*)(kp + (size_t)((t + 1) * 16 + lrow) * 3072);
            n1 = *(const bf16x8*)(kp + (size_t)((t + 1) * 16 + lrow) * 3072 + 32);
        }
        f32x4 acc = {0.f, 0.f, 0.f, 0.f};
        acc = MFMA16(aq0, k0, acc);
        acc = MFMA16(aq1, k1, acc);
        int key = t * 16 + lrow;
        for (int r = 0; r < 4; r++) {
            int qrow = r0 + g * 4 + r;
            float s = (key <= qrow) ? acc[r] * scale : -1e30f;
            float nm = fmaxf(m4[r], s);
            l4[r] = l4[r] * __expf(m4[r] - nm) + __expf(s - nm);
            m4[r] = nm;
        }
        k0 = n0; k1 = n1;
    }
    for (int r = 0; r < 4; r++) {
        float m = m4[r], l = l4[r];
        for (int off = 1; off < 16; off <<= 1) {
            float om = __shfl_xor(m, off);
            float ol = __shfl_xor(l, off);
            float nm = fmaxf(m, om);
            l = l * __expf(m - nm) + ol * __expf(om - nm);
            m = nm;
        }
        m4[r] = m; l4[r] = l;
    }
    if (lrow == 0) {
        for (int r = 0; r < 4; r++) {
            int row = r0 + g * 4 + r;
            Obuf[h * S_LEN + row] = -(m4[r] * 1.44269504f) - log2f(l4[r]);
        }
    }
}

// ---------------------------------------------------------------------------
// attn_fused: swapped-operand single-pass attention.
// Block = (64 q rows, head), 4 waves; wave owns 16 q rows.
// S^T = mfma(K, Q): lane holds fixed q, consecutive kv -> float4 P stores,
// ds_write_b64 bf16 P into wave-private LDS (no barriers), PV = mfma(VT, P).
// Also zero-fills this band's masked tail columns.
// ---------------------------------------------------------------------------
__global__ __launch_bounds__(256)
void attn_fused(const __bf16* __restrict__ qkv, const __bf16* __restrict__ vt,
                const float* __restrict__ Obuf, float* __restrict__ P,
                __bf16* __restrict__ ctx)
{
    __shared__ char Plds[4 * 4096];   // per-wave [16 q][128 kv] bf16, swizzled
    const int tid = threadIdx.x;
    const int lane = tid & 63;
    const int w = tid >> 6;
    const int lrow = lane & 15;
    const int g = lane >> 4;
    const int band = 31 - (int)blockIdx.x;   // heavy first
    const int h = blockIdx.y;
    const int qg = band * 64 + w * 16 + lrow;   // this lane's q row
    const int ntiles = band / 2 + 1;
    const float c1 = 0.18033688f;  // 0.125 * log2(e)

    const __bf16* ksec = qkv + 1024;
    const size_t Pb = (size_t)h * S_LEN * S_LEN;
    char* plB = Plds + w * 4096;

    // hoisted Q B-frags (col = q = lane&15, k = d contiguous)
    bf16x8 qf[2];
    qf[0] = *(const bf16x8*)(qkv + (size_t)qg * 3072 + h * DK + g * 8);
    qf[1] = *(const bf16x8*)(qkv + (size_t)qg * 3072 + h * DK + 32 + g * 8);
    const float offv = Obuf[h * S_LEN + qg];

    f32x4 acc2[4];   // ctx^T accumulator: md over d (4x16), cols = wave's 16 q
    for (int i = 0; i < 4; i++) acc2[i] = (f32x4){0.f, 0.f, 0.f, 0.f};

    for (int kt = 0; kt < ntiles; kt++) {
        // ---- QK^T (S^T): acc[mf] = scores for kv frag mf, this lane's q ----
        f32x4 acc[8];
        for (int mf = 0; mf < 8; mf++) acc[mf] = (f32x4){0.f, 0.f, 0.f, 0.f};
        const __bf16* kbase = ksec + (size_t)(kt * 128 + lrow) * 3072 + h * DK + g * 8;
        for (int kk = 0; kk < 2; kk++) {
            for (int mf = 0; mf < 8; mf++) {
                bf16x8 kf = *(const bf16x8*)(kbase + (size_t)(mf * 16) * 3072 + kk * 32);
                acc[mf] = MFMA16(kf, qf[kk], acc[mf]);
            }
        }
        // ---- mask + exp + P store + LDS stage ----
        for (int mf = 0; mf < 8; mf++) {
            int kvb = kt * 128 + mf * 16 + g * 4;
            float p[4];
            for (int r = 0; r < 4; r++) {
                float pv = exp2f(acc[mf][r] * c1 + offv);
                p[r] = (kvb + r <= qg) ? pv : 0.f;
            }
            float4 st = {p[0], p[1], p[2], p[3]};
            *(float4*)(P + Pb + (size_t)qg * S_LEN + kvb) = st;
            uint2 pk;
            pk.x = pack_bf16x2(p[0], p[1]);
            pk.y = pack_bf16x2(p[2], p[3]);
            int boff = (lrow * 256 + mf * 32 + g * 8) ^ ((lrow & 7) << 4);
            *(uint2*)(plB + boff) = pk;
        }
        // ---- PV: ctx^T += mfma(VT frag, P frag) ----
        for (int ks = 0; ks < 4; ks++) {
            int broff = (lrow * 256 + ks * 64 + g * 16) ^ ((lrow & 7) << 4);
            bf16x8 pf = *(bf16x8*)(plB + broff);
            const __bf16* vp = vt + (size_t)(h * DK + lrow) * S_LEN + kt * 128 + ks * 32 + g * 8;
            for (int md = 0; md < 4; md++) {
                bf16x8 vf = *(const bf16x8*)(vp + (size_t)(md * 16) * S_LEN);
                acc2[md] = MFMA16(vf, pf, acc2[md]);
            }
        }
    }

    // ---- ctx^T write: lane holds fixed q, 4 consecutive d per md ----
    for (int md = 0; md < 4; md++) {
        uint2 pk;
        pk.x = pack_bf16x2(acc2[md][0], acc2[md][1]);
        pk.y = pack_bf16x2(acc2[md][2], acc2[md][3]);
        *(uint2*)(ctx + (size_t)qg * D_MOD + h * DK + md * 16 + g * 4) = pk;
    }

    // ---- zero-fill masked tail columns of this band ----
    int z0 = ntiles * 128;
    if (z0 < S_LEN) {
        int zc = (S_LEN - z0) >> 2;   // float4 count per row
        float4 z = {0.f, 0.f, 0.f, 0.f};
        for (int r = w * 16; r < w * 16 + 16; r++) {
            float4* dst = (float4*)(P + Pb + (size_t)(band * 64 + r) * S_LEN + z0);
            for (int c = lane; c < zc; c += 64) dst[c] = z;
        }
    }
}

// ---------------------------------------------------------------------------
extern "C" void kernel_launch(void* const* d_in, const int* in_sizes, int n_in,
                              void* d_out, int out_size, void* d_ws, size_t ws_size,
                              hipStream_t stream)
{
    const float* x     = (const float*)d_in[0];
    const float* g1    = (const float*)d_in[1];
    const float* beta1 = (const float*)d_in[2];
    const float* W_in  = (const float*)d_in[3];
    const float* b_in  = (const float*)d_in[4];
    const float* Wq    = (const float*)d_in[5];
    const float* bq    = (const float*)d_in[6];
    const float* Wk    = (const float*)d_in[7];
    const float* bk    = (const float*)d_in[8];
    const float* Wv    = (const float*)d_in[9];
    const float* bv    = (const float*)d_in[10];
    const float* Wo    = (const float*)d_in[11];
    const float* bo    = (const float*)d_in[12];
    const float* W2    = (const float*)d_in[13];
    const float* b2    = (const float*)d_in[14];
    const float* g2    = (const float*)d_in[15];
    const float* beta2 = (const float*)d_in[16];
    const float* Wf1   = (const float*)d_in[17];
    const float* bf1   = (const float*)d_in[18];
    const float* Wf2   = (const float*)d_in[19];
    const float* bf2   = (const float*)d_in[20];

    float* outp = (float*)d_out;                    // [2048][1024]
    float* Pout = outp + (size_t)S_LEN * D_MOD;     // [16][2048][2048]

    char* p = (char*)d_ws;
    auto alloc = [&](size_t b) -> void* {
        void* r = (void*)p;
        p += (b + 255) & ~(size_t)255;
        return r;
    };
    __bf16* WqkvT    = (__bf16*)alloc((size_t)3072 * 1024 * 2);
    __bf16* W2T      = (__bf16*)alloc((size_t)1024 * 1024 * 2);
    __bf16* Wf1T     = (__bf16*)alloc((size_t)D_FF * D_MOD * 2);
    __bf16* Wf2T     = (__bf16*)alloc((size_t)D_MOD * D_FF * 2);
    __bf16* WqkvCT   = (__bf16*)alloc((size_t)3072 * 1024 * 2);
    __bf16* WcombT   = (__bf16*)alloc((size_t)1024 * 1024 * 2);
    float*  bqkv     = (float*)alloc((size_t)3072 * 4);
    float*  bcomb    = (float*)alloc((size_t)1024 * 4);
    float*  biaspart = (float*)alloc((size_t)8 * 4096 * 4);
    __bf16* xn_b     = (__bf16*)alloc((size_t)S_LEN * D_MOD * 2);
    __bf16* qkv_b    = (__bf16*)alloc((size_t)S_LEN * 3072 * 2);
    __bf16* VT       = (__bf16*)alloc((size_t)N_HEADS * DK * S_LEN * 2);
    __bf16* ctx_b    = (__bf16*)alloc((size_t)S_LEN * D_MOD * 2);
    float*  part1f   = (float*)alloc((size_t)S_LEN * D_MOD * 4);
    float*  norm2f   = (float*)alloc((size_t)S_LEN * D_MOD * 4);
    __bf16* norm2b   = (__bf16*)alloc((size_t)S_LEN * D_MOD * 2);
    __bf16* ff1_b    = (__bf16*)alloc((size_t)S_LEN * D_FF * 2);
    float*  Obuf     = (float*)alloc((size_t)N_HEADS * S_LEN * 4);
    // aliases: weight staging only needed before part1f/norm2f are written
    __bf16* Win_b = (__bf16*)part1f;
    __bf16* Wo_b  = (__bf16*)norm2f;

    dim3 blk(256);

    // --- weight prep ---
    transpose_f32_bf16<<<dim3(32, 32), blk, 0, stream>>>(Wq, WqkvT, 1024, 1024);
    transpose_f32_bf16<<<dim3(32, 32), blk, 0, stream>>>(Wk, WqkvT + 1024 * 1024, 1024, 1024);
    transpose_f32_bf16<<<dim3(32, 32), blk, 0, stream>>>(Wv, WqkvT + 2 * 1024 * 1024, 1024, 1024);
    transpose_f32_bf16<<<dim3(32, 32), blk, 0, stream>>>(W2, W2T, 1024, 1024);
    transpose_f32_bf16<<<dim3(128, 32), blk, 0, stream>>>(Wf1, Wf1T, 1024, 4096);
    transpose_f32_bf16<<<dim3(32, 128), blk, 0, stream>>>(Wf2, Wf2T, 4096, 1024);
    convert_f32_bf16<<<dim3(1024), blk, 0, stream>>>(W_in, Win_b);
    convert_f32_bf16<<<dim3(1024), blk, 0, stream>>>(Wo, Wo_b);
    bias_stage1<<<dim3(16, 8), blk, 0, stream>>>(b_in, bo, Wq, Wk, Wv, W2, biaspart);
    bias_stage2<<<dim3(16), blk, 0, stream>>>(biaspart, bq, bk, bv, b2, bqkv, bcomb);

    // (Win·Wqkv)^T and (Wo·W2)^T
    gemm_kernel<64, false, false, false, true><<<dim3(16, 24), blk, 0, stream>>>(
        WqkvT, Win_b, nullptr, nullptr, nullptr, WqkvCT, 3072, 1024, 1024);
    gemm_kernel<64, false, false, false, true><<<dim3(16, 8), blk, 0, stream>>>(
        W2T, Wo_b, nullptr, nullptr, nullptr, WcombT, 1024, 1024, 1024);

    // --- forward ---
    ln_kernel<<<S_LEN, blk, 0, stream>>>(x, g1, beta1, xn_b, nullptr);

    gemm_kernel<128, false, false, false, true><<<dim3(24, 16), blk, 0, stream>>>(
        xn_b, WqkvCT, bqkv, nullptr, nullptr, qkv_b, 2048, 3072, 1024);

    vhead_transpose<<<dim3(64, 2, 16), blk, 0, stream>>>(qkv_b + 2048, VT);

    attn_stats<<<dim3(32, 16), blk, 0, stream>>>(qkv_b, Obuf);
    attn_fused<<<dim3(32, 16), blk, 0, stream>>>(qkv_b, VT, Obuf, Pout, ctx_b);

    gemm_kernel<64, false, true, true, false><<<dim3(16, 16), blk, 0, stream>>>(
        ctx_b, WcombT, bcomb, x, part1f, nullptr, 2048, 1024, 1024);

    ln_kernel<<<S_LEN, blk, 0, stream>>>(part1f, g2, beta2, norm2b, norm2f);

    gemm_kernel<128, true, false, false, true><<<dim3(32, 16), blk, 0, stream>>>(
        norm2b, Wf1T, bf1, nullptr, nullptr, ff1_b, 2048, 4096, 1024);

    gemm_kernel<64, false, true, true, false><<<dim3(16, 16), blk, 0, stream>>>(
        ff1_b, Wf2T, bf2, norm2f, outp, nullptr, 2048, 1024, 4096);
}

// Round 5
// 414.164 us; speedup vs baseline: 2.8052x; 1.7007x over previous
//
#include <hip/hip_runtime.h>
#include <hip/hip_bf16.h>
#include <cstdint>

#define S_LEN 2048
#define D_MOD 1024
#define N_HEADS 16
#define DK 64
#define D_FF 4096

typedef __bf16 bf16x8 __attribute__((ext_vector_type(8)));
typedef float f32x4 __attribute__((ext_vector_type(4)));

#define MFMA16(a, b, c) __builtin_amdgcn_mfma_f32_16x16x32_bf16((a), (b), (c), 0, 0, 0)

__device__ inline unsigned pack_bf16x2(float a, float b)
{
    unsigned short ua = __builtin_bit_cast(unsigned short, (__bf16)a);
    unsigned short ub = __builtin_bit_cast(unsigned short, (__bf16)b);
    return (unsigned)ua | ((unsigned)ub << 16);
}

// async global->LDS, 16B per lane; LDS dest must be wave-uniform-base + lane*16
__device__ inline void gload16(const void* g, void* l)
{
    __builtin_amdgcn_global_load_lds(
        (const __attribute__((address_space(1))) unsigned int*)g,
        (__attribute__((address_space(3))) unsigned int*)l, 16, 0, 0);
}

// ---------------------------------------------------------------------------
// Weight transpose + f32->bf16:  W[K][N] f32 -> WT[N][K] bf16
// ---------------------------------------------------------------------------
__global__ __launch_bounds__(256)
void transpose_f32_bf16(const float* __restrict__ W, __bf16* __restrict__ WT, int K, int N)
{
    __shared__ float tile[32][33];
    int tx = threadIdx.x & 31, ty = threadIdx.x >> 5;
    int n0 = blockIdx.x * 32, k0 = blockIdx.y * 32;
    for (int i = 0; i < 4; i++)
        tile[ty + i * 8][tx] = W[(size_t)(k0 + ty + i * 8) * N + n0 + tx];
    __syncthreads();
    for (int i = 0; i < 4; i++)
        WT[(size_t)(n0 + ty + i * 8) * K + k0 + tx] = (__bf16)tile[tx][ty + i * 8];
}

__global__ __launch_bounds__(256)
void convert_f32_bf16(const float* __restrict__ W, __bf16* __restrict__ o)
{
    int i = (blockIdx.x * 256 + threadIdx.x);
    float4 v = ((const float4*)W)[i];
    uint2 pk;
    pk.x = pack_bf16x2(v.x, v.y);
    pk.y = pack_bf16x2(v.z, v.w);
    ((uint2*)o)[i] = pk;
}

// ---------------------------------------------------------------------------
// bias matvecs, two-stage parallel reduce
// ---------------------------------------------------------------------------
__global__ __launch_bounds__(256)
void bias_stage1(const float* __restrict__ b_in, const float* __restrict__ bo,
                 const float* __restrict__ Wq, const float* __restrict__ Wk,
                 const float* __restrict__ Wv, const float* __restrict__ W2,
                 float* __restrict__ part)
{
    int n = blockIdx.x * 256 + threadIdx.x;
    int kc = blockIdx.y;
    int sel = n >> 10, col = n & 1023;
    const float* W = sel == 0 ? Wq : (sel == 1 ? Wk : (sel == 2 ? Wv : W2));
    const float* src = sel < 3 ? b_in : bo;
    float s = 0.f;
    for (int k = kc * 128; k < kc * 128 + 128; k++)
        s += src[k] * W[(size_t)k * 1024 + col];
    part[kc * 4096 + n] = s;
}

__global__ __launch_bounds__(256)
void bias_stage2(const float* __restrict__ part,
                 const float* __restrict__ bq, const float* __restrict__ bk,
                 const float* __restrict__ bv, const float* __restrict__ b2,
                 float* __restrict__ bqkv, float* __restrict__ bcomb)
{
    int n = blockIdx.x * 256 + threadIdx.x;
    int sel = n >> 10, col = n & 1023;
    float s = sel == 0 ? bq[col] : (sel == 1 ? bk[col] : (sel == 2 ? bv[col] : b2[col]));
    for (int kc = 0; kc < 8; kc++) s += part[kc * 4096 + n];
    if (n < 3072) bqkv[n] = s; else bcomb[col] = s;
}

// ---------------------------------------------------------------------------
// Per-head V transpose: qkv v-section [s][3072] -> VT[h][d][s] bf16
// ---------------------------------------------------------------------------
__global__ __launch_bounds__(256)
void vhead_transpose(const __bf16* __restrict__ v, __bf16* __restrict__ vt)
{
    __shared__ __bf16 tile[32][33];
    int tx = threadIdx.x & 31, ty = threadIdx.x >> 5;
    int s0 = blockIdx.x * 32;
    int d0 = blockIdx.y * 32;
    int h = blockIdx.z;
    for (int i = 0; i < 4; i++)
        tile[ty + i * 8][tx] = v[(size_t)(s0 + ty + i * 8) * 3072 + h * DK + d0 + tx];
    __syncthreads();
    for (int i = 0; i < 4; i++)
        vt[(size_t)(h * DK + d0 + ty + i * 8) * S_LEN + s0 + tx] = tile[tx][ty + i * 8];
}

// ---------------------------------------------------------------------------
// LayerNorm
// ---------------------------------------------------------------------------
__global__ __launch_bounds__(256)
void ln_kernel(const float* __restrict__ x, const float* __restrict__ gamma,
               const float* __restrict__ beta, __bf16* __restrict__ outb,
               float* __restrict__ outf)
{
    int row = blockIdx.x;
    int tid = threadIdx.x;
    const float4 v = ((const float4*)(x + (size_t)row * D_MOD))[tid];
    float s = v.x + v.y + v.z + v.w;
    float sq = v.x * v.x + v.y * v.y + v.z * v.z + v.w * v.w;
    for (int off = 32; off; off >>= 1) {
        s += __shfl_down(s, off);
        sq += __shfl_down(sq, off);
    }
    __shared__ float red[8];
    int wid = tid >> 6;
    if ((tid & 63) == 0) { red[wid] = s; red[wid + 4] = sq; }
    __syncthreads();
    s = red[0] + red[1] + red[2] + red[3];
    sq = red[4] + red[5] + red[6] + red[7];
    float mean = s * (1.f / D_MOD);
    float var = sq * (1.f / D_MOD) - mean * mean;
    var = fmaxf(var, 0.f);
    float inv = 1.f / (sqrtf(var) + 1e-6f);
    float4 gv = ((const float4*)gamma)[tid];
    float4 bv = ((const float4*)beta)[tid];
    float y0 = gv.x * ((v.x - mean) * inv) + bv.x;
    float y1 = gv.y * ((v.y - mean) * inv) + bv.y;
    float y2 = gv.z * ((v.z - mean) * inv) + bv.z;
    float y3 = gv.w * ((v.w - mean) * inv) + bv.w;
    uint2 pk;
    pk.x = pack_bf16x2(y0, y1);
    pk.y = pack_bf16x2(y2, y3);
    ((uint2*)(outb + (size_t)row * D_MOD))[tid] = pk;
    if (outf) {
        float4 o = {y0, y1, y2, y3};
        ((float4*)(outf + (size_t)row * D_MOD))[tid] = o;
    }
}

// ---------------------------------------------------------------------------
// GEMM: C[M][N] = A[M][K](bf16) * BT[N][K](bf16) + bias; 128xBN tile, BK=64
// m97-style: global_load_lds width-16 staging into LINEAR LDS.
// ---------------------------------------------------------------------------
template<int BN, bool RELU, bool RES, bool WF32, bool WBF16>
__global__ __launch_bounds__(256, 2)
void gemm_kernel(const __bf16* __restrict__ A, const __bf16* __restrict__ BT,
                 const float* __restrict__ bias, const float* __restrict__ res,
                 float* __restrict__ Cf, __bf16* __restrict__ Cb,
                 int M, int N, int K)
{
    constexpr int NFRAG = BN / 32;
    __shared__ uint4 As[128 * 8];   // [row][8 x 16B] linear
    __shared__ uint4 Bs[BN * 8];
    const int tid = threadIdx.x;
    const int lane = tid & 63;
    const int w = tid >> 6;
    const int lrow = lane & 15;
    const int g = lane >> 4;
    const int bm = blockIdx.y * 128;
    const int bn = blockIdx.x * BN;
    const int wrow = (w >> 1) * 64;
    const int wcol = (w & 1) * (BN / 2);

    f32x4 acc[4][NFRAG];
    for (int m = 0; m < 4; m++)
        for (int n = 0; n < NFRAG; n++)
            acc[m][n] = (f32x4){0.f, 0.f, 0.f, 0.f};

    const int srow = tid >> 3;   // 0..31
    const int sc = tid & 7;      // 16B chunk
    const __bf16* Ag = A + (size_t)(bm + srow) * K + sc * 8;
    const __bf16* Bg = BT + (size_t)(bn + srow) * K + sc * 8;

    for (int kt = 0; kt < K; kt += 64) {
        __syncthreads();   // previous iteration's LDS reads complete
        #pragma unroll
        for (int p = 0; p < 4; p++)
            gload16(Ag + (size_t)(p * 32) * K + kt, &As[(srow + p * 32) * 8 + sc]);
        #pragma unroll
        for (int p = 0; p < NFRAG; p++)
            gload16(Bg + (size_t)(p * 32) * K + kt, &Bs[(srow + p * 32) * 8 + sc]);
        asm volatile("s_waitcnt vmcnt(0)" ::: "memory");
        __syncthreads();
        #pragma unroll
        for (int kk = 0; kk < 2; kk++) {
            bf16x8 af[4], bfr[NFRAG];
            int c = kk * 4 + g;
            #pragma unroll
            for (int m = 0; m < 4; m++)
                af[m] = __builtin_bit_cast(bf16x8, As[(wrow + m * 16 + lrow) * 8 + c]);
            #pragma unroll
            for (int n = 0; n < NFRAG; n++)
                bfr[n] = __builtin_bit_cast(bf16x8, Bs[(wcol + n * 16 + lrow) * 8 + c]);
            #pragma unroll
            for (int m = 0; m < 4; m++)
                #pragma unroll
                for (int n = 0; n < NFRAG; n++)
                    acc[m][n] = MFMA16(af[m], bfr[n], acc[m][n]);
        }
    }

    for (int n = 0; n < NFRAG; n++) {
        int col = bn + wcol + n * 16 + lrow;
        float bval = bias ? bias[col] : 0.f;
        for (int m = 0; m < 4; m++) {
            int row0 = bm + wrow + m * 16 + g * 4;
            for (int r = 0; r < 4; r++) {
                int row = row0 + r;
                float v = acc[m][n][r] + bval;
                if (RELU) v = fmaxf(v, 0.f);
                if (RES) v += res[(size_t)row * N + col];
                if (WF32) Cf[(size_t)row * N + col] = v;
                if (WBF16) Cb[(size_t)row * N + col] = (__bf16)v;
            }
        }
    }
}

// ---------------------------------------------------------------------------
// attn_fused v2: wave-autonomous two-pass attention, stats folded in.
// 4 waves/block, wave owns a 16-q-row band; bands paired for balance.
// Pass A: QK^T -> in-register (m,l). Pass B: QK^T -> normalized P (nt stores)
// + LDS bf16 stage -> PV. Zero-fills masked tail. No barriers at all.
// ---------------------------------------------------------------------------
__global__ __launch_bounds__(256)
void attn_fused(const __bf16* __restrict__ qkv, const __bf16* __restrict__ vt,
                float* __restrict__ P, __bf16* __restrict__ ctx)
{
    __shared__ char Plds[4 * 4096];   // per-wave [16 q][128 kv] bf16, swizzled
    const int tid = threadIdx.x;
    const int lane = tid & 63;
    const int w = tid >> 6;
    const int lrow = lane & 15;
    const int g = lane >> 4;
    const int bid = blockIdx.x;       // 0..31
    const int band = (w == 0) ? 2 * bid : (w == 1) ? 2 * bid + 1
                   : (w == 2) ? 126 - 2 * bid : 127 - 2 * bid;
    const int h = blockIdx.y;
    const int qg = band * 16 + lrow;          // this lane's q row
    const int ntiles = band / 8 + 1;          // causal 128-wide kv tiles
    const float c1 = 0.18033688f;             // 0.125 * log2(e)

    const __bf16* ksec = qkv + 1024;
    const size_t Pb = (size_t)h * S_LEN * S_LEN;
    char* plB = Plds + w * 4096;

    bf16x8 qf[2];
    qf[0] = *(const bf16x8*)(qkv + (size_t)qg * 3072 + h * DK + g * 8);
    qf[1] = *(const bf16x8*)(qkv + (size_t)qg * 3072 + h * DK + 32 + g * 8);

    // ---- pass A: row max m2 (base-2 domain) and sum l ----
    float m2 = -1e30f, l = 0.f;
    for (int kt = 0; kt < ntiles; kt++) {
        f32x4 acc[8];
        #pragma unroll
        for (int mf = 0; mf < 8; mf++) acc[mf] = (f32x4){0.f, 0.f, 0.f, 0.f};
        const __bf16* kbase = ksec + (size_t)(kt * 128 + lrow) * 3072 + h * DK + g * 8;
        #pragma unroll
        for (int kk = 0; kk < 2; kk++)
            #pragma unroll
            for (int mf = 0; mf < 8; mf++) {
                bf16x8 kf = *(const bf16x8*)(kbase + (size_t)(mf * 16) * 3072 + kk * 32);
                acc[mf] = MFMA16(kf, qf[kk], acc[mf]);
            }
        float s[8][4];
        float mx[8];
        #pragma unroll
        for (int mf = 0; mf < 8; mf++) {
            int kvb = kt * 128 + mf * 16 + g * 4;
            #pragma unroll
            for (int r = 0; r < 4; r++)
                s[mf][r] = (kvb + r <= qg) ? acc[mf][r] * c1 : -1e30f;
            mx[mf] = fmaxf(fmaxf(s[mf][0], s[mf][1]), fmaxf(s[mf][2], s[mf][3]));
        }
        float tm = fmaxf(fmaxf(fmaxf(mx[0], mx[1]), fmaxf(mx[2], mx[3])),
                         fmaxf(fmaxf(mx[4], mx[5]), fmaxf(mx[6], mx[7])));
        float nm = fmaxf(m2, tm);
        float sum = 0.f;
        #pragma unroll
        for (int mf = 0; mf < 8; mf++) {
            float e0 = exp2f(s[mf][0] - nm), e1 = exp2f(s[mf][1] - nm);
            float e2 = exp2f(s[mf][2] - nm), e3 = exp2f(s[mf][3] - nm);
            sum += (e0 + e1) + (e2 + e3);
        }
        l = l * exp2f(m2 - nm) + sum;
        m2 = nm;
    }
    // combine across the 4 g-groups holding the same q row
    #pragma unroll
    for (int off = 16; off <= 32; off <<= 1) {
        float om = __shfl_xor(m2, off);
        float ol = __shfl_xor(l, off);
        float nm = fmaxf(m2, om);
        l = l * exp2f(m2 - nm) + ol * exp2f(om - nm);
        m2 = nm;
    }
    const float offv = -m2 - log2f(l);

    // ---- pass B: normalized P + PV ----
    f32x4 acc2[4];
    #pragma unroll
    for (int i = 0; i < 4; i++) acc2[i] = (f32x4){0.f, 0.f, 0.f, 0.f};

    for (int kt = 0; kt < ntiles; kt++) {
        f32x4 acc[8];
        #pragma unroll
        for (int mf = 0; mf < 8; mf++) acc[mf] = (f32x4){0.f, 0.f, 0.f, 0.f};
        const __bf16* kbase = ksec + (size_t)(kt * 128 + lrow) * 3072 + h * DK + g * 8;
        #pragma unroll
        for (int kk = 0; kk < 2; kk++)
            #pragma unroll
            for (int mf = 0; mf < 8; mf++) {
                bf16x8 kf = *(const bf16x8*)(kbase + (size_t)(mf * 16) * 3072 + kk * 32);
                acc[mf] = MFMA16(kf, qf[kk], acc[mf]);
            }
        #pragma unroll
        for (int mf = 0; mf < 8; mf++) {
            int kvb = kt * 128 + mf * 16 + g * 4;
            float p0 = (kvb + 0 <= qg) ? exp2f(acc[mf][0] * c1 + offv) : 0.f;
            float p1 = (kvb + 1 <= qg) ? exp2f(acc[mf][1] * c1 + offv) : 0.f;
            float p2 = (kvb + 2 <= qg) ? exp2f(acc[mf][2] * c1 + offv) : 0.f;
            float p3 = (kvb + 3 <= qg) ? exp2f(acc[mf][3] * c1 + offv) : 0.f;
            f32x4 st = {p0, p1, p2, p3};
            __builtin_nontemporal_store(st, (f32x4*)(P + Pb + (size_t)qg * S_LEN + kvb));
            uint2 pk;
            pk.x = pack_bf16x2(p0, p1);
            pk.y = pack_bf16x2(p2, p3);
            *(uint2*)(plB + ((lrow * 256 + mf * 32 + g * 8) ^ ((lrow & 7) << 4))) = pk;
        }
        #pragma unroll
        for (int ks = 0; ks < 4; ks++) {
            bf16x8 pf = *(bf16x8*)(plB + ((lrow * 256 + ks * 64 + g * 16) ^ ((lrow & 7) << 4)));
            const __bf16* vp = vt + (size_t)(h * DK + lrow) * S_LEN + kt * 128 + ks * 32 + g * 8;
            #pragma unroll
            for (int md = 0; md < 4; md++) {
                bf16x8 vf = *(const bf16x8*)(vp + (size_t)(md * 16) * S_LEN);
                acc2[md] = MFMA16(vf, pf, acc2[md]);
            }
        }
    }

    // ctx^T write: lane = fixed q, 4 consecutive d per md
    #pragma unroll
    for (int md = 0; md < 4; md++) {
        uint2 pk;
        pk.x = pack_bf16x2(acc2[md][0], acc2[md][1]);
        pk.y = pack_bf16x2(acc2[md][2], acc2[md][3]);
        *(uint2*)(ctx + (size_t)qg * D_MOD + h * DK + md * 16 + g * 4) = pk;
    }

    // zero-fill masked tail columns of this lane's row
    const int z0 = ntiles * 128;
    f32x4 z = {0.f, 0.f, 0.f, 0.f};
    for (int c = z0 + g * 4; c < S_LEN; c += 16)
        __builtin_nontemporal_store(z, (f32x4*)(P + Pb + (size_t)qg * S_LEN + c));
}

// ---------------------------------------------------------------------------
extern "C" void kernel_launch(void* const* d_in, const int* in_sizes, int n_in,
                              void* d_out, int out_size, void* d_ws, size_t ws_size,
                              hipStream_t stream)
{
    const float* x     = (const float*)d_in[0];
    const float* g1    = (const float*)d_in[1];
    const float* beta1 = (const float*)d_in[2];
    const float* W_in  = (const float*)d_in[3];
    const float* b_in  = (const float*)d_in[4];
    const float* Wq    = (const float*)d_in[5];
    const float* bq    = (const float*)d_in[6];
    const float* Wk    = (const float*)d_in[7];
    const float* bk    = (const float*)d_in[8];
    const float* Wv    = (const float*)d_in[9];
    const float* bv    = (const float*)d_in[10];
    const float* Wo    = (const float*)d_in[11];
    const float* bo    = (const float*)d_in[12];
    const float* W2    = (const float*)d_in[13];
    const float* b2    = (const float*)d_in[14];
    const float* g2    = (const float*)d_in[15];
    const float* beta2 = (const float*)d_in[16];
    const float* Wf1   = (const float*)d_in[17];
    const float* bf1   = (const float*)d_in[18];
    const float* Wf2   = (const float*)d_in[19];
    const float* bf2   = (const float*)d_in[20];

    float* outp = (float*)d_out;                    // [2048][1024]
    float* Pout = outp + (size_t)S_LEN * D_MOD;     // [16][2048][2048]

    char* p = (char*)d_ws;
    auto alloc = [&](size_t b) -> void* {
        void* r = (void*)p;
        p += (b + 255) & ~(size_t)255;
        return r;
    };
    __bf16* WqkvT    = (__bf16*)alloc((size_t)3072 * 1024 * 2);
    __bf16* W2T      = (__bf16*)alloc((size_t)1024 * 1024 * 2);
    __bf16* Wf1T     = (__bf16*)alloc((size_t)D_FF * D_MOD * 2);
    __bf16* Wf2T     = (__bf16*)alloc((size_t)D_MOD * D_FF * 2);
    __bf16* WqkvCT   = (__bf16*)alloc((size_t)3072 * 1024 * 2);
    __bf16* WcombT   = (__bf16*)alloc((size_t)1024 * 1024 * 2);
    float*  bqkv     = (float*)alloc((size_t)3072 * 4);
    float*  bcomb    = (float*)alloc((size_t)1024 * 4);
    float*  biaspart = (float*)alloc((size_t)8 * 4096 * 4);
    __bf16* xn_b     = (__bf16*)alloc((size_t)S_LEN * D_MOD * 2);
    __bf16* qkv_b    = (__bf16*)alloc((size_t)S_LEN * 3072 * 2);
    __bf16* VT       = (__bf16*)alloc((size_t)N_HEADS * DK * S_LEN * 2);
    __bf16* ctx_b    = (__bf16*)alloc((size_t)S_LEN * D_MOD * 2);
    float*  part1f   = (float*)alloc((size_t)S_LEN * D_MOD * 4);
    float*  norm2f   = (float*)alloc((size_t)S_LEN * D_MOD * 4);
    __bf16* norm2b   = (__bf16*)alloc((size_t)S_LEN * D_MOD * 2);
    __bf16* ff1_b    = (__bf16*)alloc((size_t)S_LEN * D_FF * 2);
    // aliases: weight staging only needed before part1f/norm2f are written
    __bf16* Win_b = (__bf16*)part1f;
    __bf16* Wo_b  = (__bf16*)norm2f;

    dim3 blk(256);

    // --- weight prep ---
    transpose_f32_bf16<<<dim3(32, 32), blk, 0, stream>>>(Wq, WqkvT, 1024, 1024);
    transpose_f32_bf16<<<dim3(32, 32), blk, 0, stream>>>(Wk, WqkvT + 1024 * 1024, 1024, 1024);
    transpose_f32_bf16<<<dim3(32, 32), blk, 0, stream>>>(Wv, WqkvT + 2 * 1024 * 1024, 1024, 1024);
    transpose_f32_bf16<<<dim3(32, 32), blk, 0, stream>>>(W2, W2T, 1024, 1024);
    transpose_f32_bf16<<<dim3(128, 32), blk, 0, stream>>>(Wf1, Wf1T, 1024, 4096);
    transpose_f32_bf16<<<dim3(32, 128), blk, 0, stream>>>(Wf2, Wf2T, 4096, 1024);
    convert_f32_bf16<<<dim3(1024), blk, 0, stream>>>(W_in, Win_b);
    convert_f32_bf16<<<dim3(1024), blk, 0, stream>>>(Wo, Wo_b);
    bias_stage1<<<dim3(16, 8), blk, 0, stream>>>(b_in, bo, Wq, Wk, Wv, W2, biaspart);
    bias_stage2<<<dim3(16), blk, 0, stream>>>(biaspart, bq, bk, bv, b2, bqkv, bcomb);

    // (Win·Wqkv)^T and (Wo·W2)^T
    gemm_kernel<64, false, false, false, true><<<dim3(16, 24), blk, 0, stream>>>(
        WqkvT, Win_b, nullptr, nullptr, nullptr, WqkvCT, 3072, 1024, 1024);
    gemm_kernel<64, false, false, false, true><<<dim3(16, 8), blk, 0, stream>>>(
        W2T, Wo_b, nullptr, nullptr, nullptr, WcombT, 1024, 1024, 1024);

    // --- forward ---
    ln_kernel<<<S_LEN, blk, 0, stream>>>(x, g1, beta1, xn_b, nullptr);

    gemm_kernel<128, false, false, false, true><<<dim3(24, 16), blk, 0, stream>>>(
        xn_b, WqkvCT, bqkv, nullptr, nullptr, qkv_b, 2048, 3072, 1024);

    vhead_transpose<<<dim3(64, 2, 16), blk, 0, stream>>>(qkv_b + 2048, VT);

    attn_fused<<<dim3(32, 16), blk, 0, stream>>>(qkv_b, VT, Pout, ctx_b);

    gemm_kernel<64, false, true, true, false><<<dim3(16, 16), blk, 0, stream>>>(
        ctx_b, WcombT, bcomb, x, part1f, nullptr, 2048, 1024, 1024);

    ln_kernel<<<S_LEN, blk, 0, stream>>>(part1f, g2, beta2, norm2b, norm2f);

    gemm_kernel<128, true, false, false, true><<<dim3(32, 16), blk, 0, stream>>>(
        norm2b, Wf1T, bf1, nullptr, nullptr, ff1_b, 2048, 4096, 1024);

    gemm_kernel<64, false, true, true, false><<<dim3(16, 16), blk, 0, stream>>>(
        ff1_b, Wf2T, bf2, norm2f, outp, nullptr, 2048, 1024, 4096);
}

// Round 6
// 411.022 us; speedup vs baseline: 2.8267x; 1.0076x over previous
//
#include <hip/hip_runtime.h>
#include <hip/hip_bf16.h>
#include <cstdint>

#define S_LEN 2048
#define D_MOD 1024
#define N_HEADS 16
#define DK 64
#define D_FF 4096

typedef __bf16 bf16x8 __attribute__((ext_vector_type(8)));
typedef float f32x4 __attribute__((ext_vector_type(4)));

#define MFMA16(a, b, c) __builtin_amdgcn_mfma_f32_16x16x32_bf16((a), (b), (c), 0, 0, 0)

__device__ inline unsigned pack_bf16x2(float a, float b)
{
    unsigned short ua = __builtin_bit_cast(unsigned short, (__bf16)a);
    unsigned short ub = __builtin_bit_cast(unsigned short, (__bf16)b);
    return (unsigned)ua | ((unsigned)ub << 16);
}

__device__ inline float bf_bits_to_f32(unsigned us)
{
    return __builtin_bit_cast(float, us << 16);
}

// async global->LDS, 16B per lane; LDS dest must be wave-uniform-base + lane*16
__device__ inline void gload16(const void* g, void* l)
{
    __builtin_amdgcn_global_load_lds(
        (const __attribute__((address_space(1))) unsigned int*)g,
        (__attribute__((address_space(3))) unsigned int*)l, 16, 0, 0);
}

// ---------------------------------------------------------------------------
// Weight transpose + f32->bf16:  W[K][N] f32 -> WT[N][K] bf16
// ---------------------------------------------------------------------------
__global__ __launch_bounds__(256)
void transpose_f32_bf16(const float* __restrict__ W, __bf16* __restrict__ WT, int K, int N)
{
    __shared__ float tile[32][33];
    int tx = threadIdx.x & 31, ty = threadIdx.x >> 5;
    int n0 = blockIdx.x * 32, k0 = blockIdx.y * 32;
    for (int i = 0; i < 4; i++)
        tile[ty + i * 8][tx] = W[(size_t)(k0 + ty + i * 8) * N + n0 + tx];
    __syncthreads();
    for (int i = 0; i < 4; i++)
        WT[(size_t)(n0 + ty + i * 8) * K + k0 + tx] = (__bf16)tile[tx][ty + i * 8];
}

__global__ __launch_bounds__(256)
void convert_f32_bf16(const float* __restrict__ W, __bf16* __restrict__ o)
{
    int i = (blockIdx.x * 256 + threadIdx.x);
    float4 v = ((const float4*)W)[i];
    uint2 pk;
    pk.x = pack_bf16x2(v.x, v.y);
    pk.y = pack_bf16x2(v.z, v.w);
    ((uint2*)o)[i] = pk;
}

// ---------------------------------------------------------------------------
// bias matvecs, two-stage parallel reduce
// ---------------------------------------------------------------------------
__global__ __launch_bounds__(256)
void bias_stage1(const float* __restrict__ b_in, const float* __restrict__ bo,
                 const float* __restrict__ Wq, const float* __restrict__ Wk,
                 const float* __restrict__ Wv, const float* __restrict__ W2,
                 float* __restrict__ part)
{
    int n = blockIdx.x * 256 + threadIdx.x;
    int kc = blockIdx.y;
    int sel = n >> 10, col = n & 1023;
    const float* W = sel == 0 ? Wq : (sel == 1 ? Wk : (sel == 2 ? Wv : W2));
    const float* src = sel < 3 ? b_in : bo;
    float s = 0.f;
    for (int k = kc * 128; k < kc * 128 + 128; k++)
        s += src[k] * W[(size_t)k * 1024 + col];
    part[kc * 4096 + n] = s;
}

__global__ __launch_bounds__(256)
void bias_stage2(const float* __restrict__ part,
                 const float* __restrict__ bq, const float* __restrict__ bk,
                 const float* __restrict__ bv, const float* __restrict__ b2,
                 float* __restrict__ bqkv, float* __restrict__ bcomb)
{
    int n = blockIdx.x * 256 + threadIdx.x;
    int sel = n >> 10, col = n & 1023;
    float s = sel == 0 ? bq[col] : (sel == 1 ? bk[col] : (sel == 2 ? bv[col] : b2[col]));
    for (int kc = 0; kc < 8; kc++) s += part[kc * 4096 + n];
    if (n < 3072) bqkv[n] = s; else bcomb[col] = s;
}

// ---------------------------------------------------------------------------
// Per-head V transpose: qkv v-section [s][3072] -> VT[h][d][s] bf16
// ---------------------------------------------------------------------------
__global__ __launch_bounds__(256)
void vhead_transpose(const __bf16* __restrict__ v, __bf16* __restrict__ vt)
{
    __shared__ __bf16 tile[32][33];
    int tx = threadIdx.x & 31, ty = threadIdx.x >> 5;
    int s0 = blockIdx.x * 32;
    int d0 = blockIdx.y * 32;
    int h = blockIdx.z;
    for (int i = 0; i < 4; i++)
        tile[ty + i * 8][tx] = v[(size_t)(s0 + ty + i * 8) * 3072 + h * DK + d0 + tx];
    __syncthreads();
    for (int i = 0; i < 4; i++)
        vt[(size_t)(h * DK + d0 + ty + i * 8) * S_LEN + s0 + tx] = tile[tx][ty + i * 8];
}

// ---------------------------------------------------------------------------
// LayerNorm
// ---------------------------------------------------------------------------
__global__ __launch_bounds__(256)
void ln_kernel(const float* __restrict__ x, const float* __restrict__ gamma,
               const float* __restrict__ beta, __bf16* __restrict__ outb,
               float* __restrict__ outf)
{
    int row = blockIdx.x;
    int tid = threadIdx.x;
    const float4 v = ((const float4*)(x + (size_t)row * D_MOD))[tid];
    float s = v.x + v.y + v.z + v.w;
    float sq = v.x * v.x + v.y * v.y + v.z * v.z + v.w * v.w;
    for (int off = 32; off; off >>= 1) {
        s += __shfl_down(s, off);
        sq += __shfl_down(sq, off);
    }
    __shared__ float red[8];
    int wid = tid >> 6;
    if ((tid & 63) == 0) { red[wid] = s; red[wid + 4] = sq; }
    __syncthreads();
    s = red[0] + red[1] + red[2] + red[3];
    sq = red[4] + red[5] + red[6] + red[7];
    float mean = s * (1.f / D_MOD);
    float var = sq * (1.f / D_MOD) - mean * mean;
    var = fmaxf(var, 0.f);
    float inv = 1.f / (sqrtf(var) + 1e-6f);
    float4 gv = ((const float4*)gamma)[tid];
    float4 bv = ((const float4*)beta)[tid];
    float y0 = gv.x * ((v.x - mean) * inv) + bv.x;
    float y1 = gv.y * ((v.y - mean) * inv) + bv.y;
    float y2 = gv.z * ((v.z - mean) * inv) + bv.z;
    float y3 = gv.w * ((v.w - mean) * inv) + bv.w;
    uint2 pk;
    pk.x = pack_bf16x2(y0, y1);
    pk.y = pack_bf16x2(y2, y3);
    ((uint2*)(outb + (size_t)row * D_MOD))[tid] = pk;
    if (outf) {
        float4 o = {y0, y1, y2, y3};
        ((float4*)(outf + (size_t)row * D_MOD))[tid] = o;
    }
}

// ---------------------------------------------------------------------------
// GEMM: C[M][N] = A[M][K](bf16) * BT[N][K](bf16) + bias; 128xBN tile, BK=64
// m97-style: global_load_lds width-16 staging into LINEAR LDS.
// ---------------------------------------------------------------------------
template<int BN, bool RELU, bool RES, bool WF32, bool WBF16>
__global__ __launch_bounds__(256, 2)
void gemm_kernel(const __bf16* __restrict__ A, const __bf16* __restrict__ BT,
                 const float* __restrict__ bias, const float* __restrict__ res,
                 float* __restrict__ Cf, __bf16* __restrict__ Cb,
                 int M, int N, int K)
{
    constexpr int NFRAG = BN / 32;
    __shared__ uint4 As[128 * 8];   // [row][8 x 16B] linear
    __shared__ uint4 Bs[BN * 8];
    const int tid = threadIdx.x;
    const int lane = tid & 63;
    const int w = tid >> 6;
    const int lrow = lane & 15;
    const int g = lane >> 4;
    const int bm = blockIdx.y * 128;
    const int bn = blockIdx.x * BN;
    const int wrow = (w >> 1) * 64;
    const int wcol = (w & 1) * (BN / 2);

    f32x4 acc[4][NFRAG];
    for (int m = 0; m < 4; m++)
        for (int n = 0; n < NFRAG; n++)
            acc[m][n] = (f32x4){0.f, 0.f, 0.f, 0.f};

    const int srow = tid >> 3;   // 0..31
    const int sc = tid & 7;      // 16B chunk
    const __bf16* Ag = A + (size_t)(bm + srow) * K + sc * 8;
    const __bf16* Bg = BT + (size_t)(bn + srow) * K + sc * 8;

    for (int kt = 0; kt < K; kt += 64) {
        __syncthreads();   // previous iteration's LDS reads complete
        #pragma unroll
        for (int p = 0; p < 4; p++)
            gload16(Ag + (size_t)(p * 32) * K + kt, &As[(srow + p * 32) * 8 + sc]);
        #pragma unroll
        for (int p = 0; p < NFRAG; p++)
            gload16(Bg + (size_t)(p * 32) * K + kt, &Bs[(srow + p * 32) * 8 + sc]);
        asm volatile("s_waitcnt vmcnt(0)" ::: "memory");
        __syncthreads();
        #pragma unroll
        for (int kk = 0; kk < 2; kk++) {
            bf16x8 af[4], bfr[NFRAG];
            int c = kk * 4 + g;
            #pragma unroll
            for (int m = 0; m < 4; m++)
                af[m] = __builtin_bit_cast(bf16x8, As[(wrow + m * 16 + lrow) * 8 + c]);
            #pragma unroll
            for (int n = 0; n < NFRAG; n++)
                bfr[n] = __builtin_bit_cast(bf16x8, Bs[(wcol + n * 16 + lrow) * 8 + c]);
            #pragma unroll
            for (int m = 0; m < 4; m++)
                #pragma unroll
                for (int n = 0; n < NFRAG; n++)
                    acc[m][n] = MFMA16(af[m], bfr[n], acc[m][n]);
        }
    }

    for (int n = 0; n < NFRAG; n++) {
        int col = bn + wcol + n * 16 + lrow;
        float bval = bias ? bias[col] : 0.f;
        for (int m = 0; m < 4; m++) {
            int row0 = bm + wrow + m * 16 + g * 4;
            for (int r = 0; r < 4; r++) {
                int row = row0 + r;
                float v = acc[m][n][r] + bval;
                if (RELU) v = fmaxf(v, 0.f);
                if (RES) v += res[(size_t)row * N + col];
                if (WF32) Cf[(size_t)row * N + col] = v;
                if (WBF16) Cb[(size_t)row * N + col] = (__bf16)v;
            }
        }
    }
}

// ---------------------------------------------------------------------------
// attn_fused v3: block = (16-row band, head); 4 waves split kv tiles.
// Pass A: partial (m,l) per wave -> LDS combine (1 barrier).
// Pass B: QK^T -> P (bf16 LDS stage -> coalesced f32 copy-out) + partial PV.
// PV partials combined via LDS (reusing the P stage buffer, 1 barrier).
// ---------------------------------------------------------------------------
__global__ __launch_bounds__(256)
void attn_fused(const __bf16* __restrict__ qkv, const __bf16* __restrict__ vt,
                float* __restrict__ P, __bf16* __restrict__ ctx)
{
    __shared__ char Plds[4][4096];          // per-wave [16 q][128 kv] bf16 swz; then f32 reduce buf
    __shared__ float cmw[4][16], clw[4][16];
    const int tid = threadIdx.x;
    const int lane = tid & 63;
    const int w = tid >> 6;
    const int lrow = lane & 15;
    const int g = lane >> 4;
    const int band = 127 - (int)blockIdx.x;   // heavy first
    const int h = blockIdx.y;
    const int qg = band * 16 + lrow;          // this lane's q row
    const int ntiles = band / 8 + 1;          // causal 128-wide kv tiles
    const float c1 = 0.18033688f;             // 0.125 * log2(e)

    const __bf16* ksec = qkv + 1024;
    const size_t Pb = (size_t)h * S_LEN * S_LEN;
    char* plB = Plds[w];

    bf16x8 qf[2];
    qf[0] = *(const bf16x8*)(qkv + (size_t)qg * 3072 + h * DK + g * 8);
    qf[1] = *(const bf16x8*)(qkv + (size_t)qg * 3072 + h * DK + 32 + g * 8);

    // ---- pass A: partial row max m2 (base-2 domain) and sum l over my tiles ----
    float m2 = -1e30f, l = 0.f;
    for (int kt = w; kt < ntiles; kt += 4) {
        f32x4 acc[8];
        #pragma unroll
        for (int mf = 0; mf < 8; mf++) acc[mf] = (f32x4){0.f, 0.f, 0.f, 0.f};
        const __bf16* kbase = ksec + (size_t)(kt * 128 + lrow) * 3072 + h * DK + g * 8;
        #pragma unroll
        for (int kk = 0; kk < 2; kk++)
            #pragma unroll
            for (int mf = 0; mf < 8; mf++) {
                bf16x8 kf = *(const bf16x8*)(kbase + (size_t)(mf * 16) * 3072 + kk * 32);
                acc[mf] = MFMA16(kf, qf[kk], acc[mf]);
            }
        float s[8][4];
        float mx[8];
        #pragma unroll
        for (int mf = 0; mf < 8; mf++) {
            int kvb = kt * 128 + mf * 16 + g * 4;
            #pragma unroll
            for (int r = 0; r < 4; r++)
                s[mf][r] = (kvb + r <= qg) ? acc[mf][r] * c1 : -1e30f;
            mx[mf] = fmaxf(fmaxf(s[mf][0], s[mf][1]), fmaxf(s[mf][2], s[mf][3]));
        }
        float tm = fmaxf(fmaxf(fmaxf(mx[0], mx[1]), fmaxf(mx[2], mx[3])),
                         fmaxf(fmaxf(mx[4], mx[5]), fmaxf(mx[6], mx[7])));
        float nm = fmaxf(m2, tm);
        float sum = 0.f;
        #pragma unroll
        for (int mf = 0; mf < 8; mf++) {
            float e0 = exp2f(s[mf][0] - nm), e1 = exp2f(s[mf][1] - nm);
            float e2 = exp2f(s[mf][2] - nm), e3 = exp2f(s[mf][3] - nm);
            sum += (e0 + e1) + (e2 + e3);
        }
        l = l * exp2f(m2 - nm) + sum;
        m2 = nm;
    }
    // combine across the 4 g-groups (lanes sharing lrow)
    #pragma unroll
    for (int off = 16; off <= 32; off <<= 1) {
        float om = __shfl_xor(m2, off);
        float ol = __shfl_xor(l, off);
        float nm = fmaxf(m2, om);
        l = l * exp2f(m2 - nm) + ol * exp2f(om - nm);
        m2 = nm;
    }
    if (lane < 16) { cmw[w][lrow] = m2; clw[w][lrow] = l; }
    __syncthreads();
    // combine across waves
    {
        float M = fmaxf(fmaxf(cmw[0][lrow], cmw[1][lrow]),
                        fmaxf(cmw[2][lrow], cmw[3][lrow]));
        float L = clw[0][lrow] * exp2f(cmw[0][lrow] - M)
                + clw[1][lrow] * exp2f(cmw[1][lrow] - M)
                + clw[2][lrow] * exp2f(cmw[2][lrow] - M)
                + clw[3][lrow] * exp2f(cmw[3][lrow] - M);
        m2 = M; l = L;
    }
    const float offv = -m2 - log2f(l);

    // ---- pass B: normalized P + partial PV over my tiles ----
    f32x4 acc2[4];
    #pragma unroll
    for (int i = 0; i < 4; i++) acc2[i] = (f32x4){0.f, 0.f, 0.f, 0.f};

    for (int kt = w; kt < ntiles; kt += 4) {
        f32x4 acc[8];
        #pragma unroll
        for (int mf = 0; mf < 8; mf++) acc[mf] = (f32x4){0.f, 0.f, 0.f, 0.f};
        const __bf16* kbase = ksec + (size_t)(kt * 128 + lrow) * 3072 + h * DK + g * 8;
        #pragma unroll
        for (int kk = 0; kk < 2; kk++)
            #pragma unroll
            for (int mf = 0; mf < 8; mf++) {
                bf16x8 kf = *(const bf16x8*)(kbase + (size_t)(mf * 16) * 3072 + kk * 32);
                acc[mf] = MFMA16(kf, qf[kk], acc[mf]);
            }
        #pragma unroll
        for (int mf = 0; mf < 8; mf++) {
            int kvb = kt * 128 + mf * 16 + g * 4;
            float p0 = (kvb + 0 <= qg) ? exp2f(acc[mf][0] * c1 + offv) : 0.f;
            float p1 = (kvb + 1 <= qg) ? exp2f(acc[mf][1] * c1 + offv) : 0.f;
            float p2 = (kvb + 2 <= qg) ? exp2f(acc[mf][2] * c1 + offv) : 0.f;
            float p3 = (kvb + 3 <= qg) ? exp2f(acc[mf][3] * c1 + offv) : 0.f;
            uint2 pk;
            pk.x = pack_bf16x2(p0, p1);
            pk.y = pack_bf16x2(p2, p3);
            *(uint2*)(plB + ((lrow * 256 + mf * 32 + g * 8) ^ ((lrow & 7) << 4))) = pk;
        }
        // PV on this tile
        #pragma unroll
        for (int ks = 0; ks < 4; ks++) {
            bf16x8 pf = *(bf16x8*)(plB + ((lrow * 256 + ks * 64 + g * 16) ^ ((lrow & 7) << 4)));
            const __bf16* vp = vt + (size_t)(h * DK + lrow) * S_LEN + kt * 128 + ks * 32 + g * 8;
            #pragma unroll
            for (int md = 0; md < 4; md++) {
                bf16x8 vf = *(const bf16x8*)(vp + (size_t)(md * 16) * S_LEN);
                acc2[md] = MFMA16(vf, pf, acc2[md]);
            }
        }
        // coalesced copy-out: P tile f32 from bf16 LDS stage
        {
            const int r2 = lane >> 5;      // 0..1
            const int cb = lane & 31;      // 8B units within a row
            #pragma unroll
            for (int it = 0; it < 8; it++) {
                int r = it * 2 + r2;
                uint2 pk = *(uint2*)(plB + ((r * 256 + cb * 8) ^ ((r & 7) << 4)));
                f32x4 v;
                v[0] = bf_bits_to_f32(pk.x & 0xffffu);
                v[1] = bf_bits_to_f32(pk.x >> 16);
                v[2] = bf_bits_to_f32(pk.y & 0xffffu);
                v[3] = bf_bits_to_f32(pk.y >> 16);
                *(f32x4*)(P + Pb + (size_t)(band * 16 + r) * S_LEN + kt * 128 + cb * 4) = v;
            }
        }
    }

    // ---- cross-wave PV reduce (reuse Plds as float[16][64] per wave) ----
    {
        float* rv = (float*)plB;
        #pragma unroll
        for (int md = 0; md < 4; md++)
            #pragma unroll
            for (int r = 0; r < 4; r++)
                rv[(md * 4 + r) * 64 + lane] = acc2[md][r];
    }
    __syncthreads();
    {
        // wave w handles md = w: d = h*64 + w*16 + g*4 + r, q = band*16 + lrow
        float v[4];
        #pragma unroll
        for (int r = 0; r < 4; r++) {
            int idx = (w * 4 + r) * 64 + lane;
            v[r] = ((float*)Plds[0])[idx] + ((float*)Plds[1])[idx]
                 + ((float*)Plds[2])[idx] + ((float*)Plds[3])[idx];
        }
        uint2 pk;
        pk.x = pack_bf16x2(v[0], v[1]);
        pk.y = pack_bf16x2(v[2], v[3]);
        *(uint2*)(ctx + (size_t)qg * D_MOD + h * DK + w * 16 + g * 4) = pk;
    }

    // ---- zero-fill masked tail columns, 1KB contiguous runs per wave ----
    const int z0 = ntiles * 128;
    if (z0 < S_LEN) {
        f32x4 z = {0.f, 0.f, 0.f, 0.f};
        for (int rr = w; rr < 16; rr += 4) {
            float* rowp = P + Pb + (size_t)(band * 16 + rr) * S_LEN;
            for (int c = z0 + lane * 4; c < S_LEN; c += 256)
                *(f32x4*)(rowp + c) = z;
        }
    }
}

// ---------------------------------------------------------------------------
extern "C" void kernel_launch(void* const* d_in, const int* in_sizes, int n_in,
                              void* d_out, int out_size, void* d_ws, size_t ws_size,
                              hipStream_t stream)
{
    const float* x     = (const float*)d_in[0];
    const float* g1    = (const float*)d_in[1];
    const float* beta1 = (const float*)d_in[2];
    const float* W_in  = (const float*)d_in[3];
    const float* b_in  = (const float*)d_in[4];
    const float* Wq    = (const float*)d_in[5];
    const float* bq    = (const float*)d_in[6];
    const float* Wk    = (const float*)d_in[7];
    const float* bk    = (const float*)d_in[8];
    const float* Wv    = (const float*)d_in[9];
    const float* bv    = (const float*)d_in[10];
    const float* Wo    = (const float*)d_in[11];
    const float* bo    = (const float*)d_in[12];
    const float* W2    = (const float*)d_in[13];
    const float* b2    = (const float*)d_in[14];
    const float* g2    = (const float*)d_in[15];
    const float* beta2 = (const float*)d_in[16];
    const float* Wf1   = (const float*)d_in[17];
    const float* bf1   = (const float*)d_in[18];
    const float* Wf2   = (const float*)d_in[19];
    const float* bf2   = (const float*)d_in[20];

    float* outp = (float*)d_out;                    // [2048][1024]
    float* Pout = outp + (size_t)S_LEN * D_MOD;     // [16][2048][2048]

    char* p = (char*)d_ws;
    auto alloc = [&](size_t b) -> void* {
        void* r = (void*)p;
        p += (b + 255) & ~(size_t)255;
        return r;
    };
    __bf16* WqkvT    = (__bf16*)alloc((size_t)3072 * 1024 * 2);
    __bf16* W2T      = (__bf16*)alloc((size_t)1024 * 1024 * 2);
    __bf16* Wf1T     = (__bf16*)alloc((size_t)D_FF * D_MOD * 2);
    __bf16* Wf2T     = (__bf16*)alloc((size_t)D_MOD * D_FF * 2);
    __bf16* WqkvCT   = (__bf16*)alloc((size_t)3072 * 1024 * 2);
    __bf16* WcombT   = (__bf16*)alloc((size_t)1024 * 1024 * 2);
    float*  bqkv     = (float*)alloc((size_t)3072 * 4);
    float*  bcomb    = (float*)alloc((size_t)1024 * 4);
    float*  biaspart = (float*)alloc((size_t)8 * 4096 * 4);
    __bf16* xn_b     = (__bf16*)alloc((size_t)S_LEN * D_MOD * 2);
    __bf16* qkv_b    = (__bf16*)alloc((size_t)S_LEN * 3072 * 2);
    __bf16* VT       = (__bf16*)alloc((size_t)N_HEADS * DK * S_LEN * 2);
    __bf16* ctx_b    = (__bf16*)alloc((size_t)S_LEN * D_MOD * 2);
    float*  part1f   = (float*)alloc((size_t)S_LEN * D_MOD * 4);
    float*  norm2f   = (float*)alloc((size_t)S_LEN * D_MOD * 4);
    __bf16* norm2b   = (__bf16*)alloc((size_t)S_LEN * D_MOD * 2);
    __bf16* ff1_b    = (__bf16*)alloc((size_t)S_LEN * D_FF * 2);
    // aliases: weight staging only needed before part1f/norm2f are written
    __bf16* Win_b = (__bf16*)part1f;
    __bf16* Wo_b  = (__bf16*)norm2f;

    dim3 blk(256);

    // --- weight prep ---
    transpose_f32_bf16<<<dim3(32, 32), blk, 0, stream>>>(Wq, WqkvT, 1024, 1024);
    transpose_f32_bf16<<<dim3(32, 32), blk, 0, stream>>>(Wk, WqkvT + 1024 * 1024, 1024, 1024);
    transpose_f32_bf16<<<dim3(32, 32), blk, 0, stream>>>(Wv, WqkvT + 2 * 1024 * 1024, 1024, 1024);
    transpose_f32_bf16<<<dim3(32, 32), blk, 0, stream>>>(W2, W2T, 1024, 1024);
    transpose_f32_bf16<<<dim3(128, 32), blk, 0, stream>>>(Wf1, Wf1T, 1024, 4096);
    transpose_f32_bf16<<<dim3(32, 128), blk, 0, stream>>>(Wf2, Wf2T, 4096, 1024);
    convert_f32_bf16<<<dim3(1024), blk, 0, stream>>>(W_in, Win_b);
    convert_f32_bf16<<<dim3(1024), blk, 0, stream>>>(Wo, Wo_b);
    bias_stage1<<<dim3(16, 8), blk, 0, stream>>>(b_in, bo, Wq, Wk, Wv, W2, biaspart);
    bias_stage2<<<dim3(16), blk, 0, stream>>>(biaspart, bq, bk, bv, b2, bqkv, bcomb);

    // (Win·Wqkv)^T and (Wo·W2)^T
    gemm_kernel<64, false, false, false, true><<<dim3(16, 24), blk, 0, stream>>>(
        WqkvT, Win_b, nullptr, nullptr, nullptr, WqkvCT, 3072, 1024, 1024);
    gemm_kernel<64, false, false, false, true><<<dim3(16, 8), blk, 0, stream>>>(
        W2T, Wo_b, nullptr, nullptr, nullptr, WcombT, 1024, 1024, 1024);

    // --- forward ---
    ln_kernel<<<S_LEN, blk, 0, stream>>>(x, g1, beta1, xn_b, nullptr);

    gemm_kernel<128, false, false, false, true><<<dim3(24, 16), blk, 0, stream>>>(
        xn_b, WqkvCT, bqkv, nullptr, nullptr, qkv_b, 2048, 3072, 1024);

    vhead_transpose<<<dim3(64, 2, 16), blk, 0, stream>>>(qkv_b + 2048, VT);

    attn_fused<<<dim3(128, 16), blk, 0, stream>>>(qkv_b, VT, Pout, ctx_b);

    gemm_kernel<64, false, true, true, false><<<dim3(16, 16), blk, 0, stream>>>(
        ctx_b, WcombT, bcomb, x, part1f, nullptr, 2048, 1024, 1024);

    ln_kernel<<<S_LEN, blk, 0, stream>>>(part1f, g2, beta2, norm2b, norm2f);

    gemm_kernel<128, true, false, false, true><<<dim3(32, 16), blk, 0, stream>>>(
        norm2b, Wf1T, bf1, nullptr, nullptr, ff1_b, 2048, 4096, 1024);

    gemm_kernel<64, false, true, true, false><<<dim3(16, 16), blk, 0, stream>>>(
        ff1_b, Wf2T, bf2, norm2f, outp, nullptr, 2048, 1024, 4096);
}